// Round 11
// baseline (588.543 us; speedup 1.0000x reference)
//
#include <hip/hip_runtime.h>
#include <hip/hip_bf16.h>
#include <math.h>

#define DEV __device__ __forceinline__

constexpr int XFv = 124;              // features per node row
constexpr size_t OPB   = 3309568;     // output floats per batch
constexpr size_t UBASE = 262144;      // dense floats per batch
constexpr size_t VBASE = 1785856;     // UBASE + 8192*186
constexpr int UVWID = 186;            // 20+32+52+82

using bfrag  = __attribute__((ext_vector_type(8))) short;   // 8 bf16
using f32x4v = __attribute__((ext_vector_type(4))) float;   // MFMA acc

// --- rotated LDS layout helpers (fp32 tiles) ---
DEV float* at4p(float* base, int t, int c0, int W) {
  return base + t * W + ((c0 + 4 * t) & (W - 1));
}
DEV float& at1r(float* base, int t, int c, int W) {
  return base[t * W + (((c & ~3) + 4 * t) & (W - 1)) + (c & 3)];
}
DEV float4 ld4g(const float* p) { return *(const float4*)p; }
DEV void fma4(float4& a, float s, const float4& w) {
  a.x += s * w.x; a.y += s * w.y; a.z += s * w.z; a.w += s * w.w;
}
// tanh-form GELU: gelu(x) ~= x * e/(e+1), e = exp(x*(c1 + c2*x^2)).
DEV float gelu_fast(float x) {
  float x2 = x * x;
  float z = x * (1.5957691216057308f + 0.0713551f * x2);
  float e = __expf(z);
  float r = 1.0f - __frcp_rn(e + 1.0f);
  return x * r;
}
// bf16 conversions through HIP intrinsics (v_cvt_pk_bf16_f32, RNE).
DEV ushort f2bf(float x) {
  __hip_bfloat16 b = __float2bfloat16(x);
  union { __hip_bfloat16 h; ushort u; } cv;
  cv.h = b;
  return cv.u;
}
DEV unsigned f2bf2(float lo, float hi) {
  __hip_bfloat162 b2 = __float22bfloat162_rn(make_float2(lo, hi));
  union { __hip_bfloat162 h; unsigned u; } cv;
  cv.h = b2;
  return cv.u;
}
// bf16 rotated row store (width 128): element (row,col)
DEV void stb128(ushort* b, int row, int col, float v) {
  b[row * 128 + (((col & ~7) + 8 * row) & 127) + (col & 7)] = f2bf(v);
}

// ============ 0a. weight prep: fp32 [K][N] -> bf16 [N][K], 4 levels ========
__global__ __launch_bounds__(256) void wprep_all_kernel(
    const float* __restrict__ src0, ushort* __restrict__ dst0, int K, int N) {
  size_t off = (size_t)blockIdx.z * K * N;
  const float* src = src0 + off;
  ushort* dst = dst0 + off;
  __shared__ float S[64][65];
  int tid = threadIdx.x;
  int k0 = blockIdx.x * 64, n0 = blockIdx.y * 64;
  for (int i = tid; i < 64 * 64; i += 256) {
    int kk = i >> 6, nn = i & 63;
    S[kk][nn] = src[(size_t)(k0 + kk) * N + n0 + nn];
  }
  __syncthreads();
  int n = tid >> 2, kq = tid & 3;
  unsigned pk[8];
#pragma unroll
  for (int i = 0; i < 8; i++) {
    int k = kq * 16 + 2 * i;
    pk[i] = f2bf2(S[k][n], S[k + 1][n]);
  }
  unsigned* dp = (unsigned*)&dst[(size_t)(n0 + n) * K + k0 + kq * 16];
#pragma unroll
  for (int i = 0; i < 8; i++) dp[i] = pk[i];
}

// ====== 0b. uv weight prep (all 8 matrices in one launch) ==================
struct UVDesc {
  const float* src[8];
  ushort* dst[8];
  int expj[8];
  int npad[8];
};
__global__ __launch_bounds__(256) void uvprep_all_kernel(UVDesc d) {
  int mi = blockIdx.y;
  int i = blockIdx.x * 256 + threadIdx.x;
  int expj = d.expj[mi];
  if (i >= d.npad[mi] * 128) return;
  int n = i >> 7, k = i & 127;
  d.dst[mi][(size_t)n * 128 + k] =
      (n < expj) ? f2bf(d.src[mi][(size_t)k * expj + n]) : (ushort)0;
}

// ====== 0c. effective node-embed weights + RoPE table ======================
__global__ __launch_bounds__(128) void weff_prep_kernel(
    const float* __restrict__ cw, const float* __restrict__ cb,
    const float* __restrict__ nw, const float* __restrict__ nb,
    const float* __restrict__ iw, const float* __restrict__ ib,
    float* __restrict__ weff, float* __restrict__ ropetab) {
  __shared__ float S[11 * 128];
  int tid = threadIdx.x;
  for (int i = tid; i < 512; i += 128) S[i] = cw[i];
  for (int i = tid; i < 640; i += 128) S[512 + i] = nw[i];
  S[1152 + tid] = nb[tid];
  S[1280 + tid] = cb[tid];
  __syncthreads();
  float acc[11];
#pragma unroll
  for (int r = 0; r < 10; r++) acc[r] = 0.f;
  acc[10] = ib[tid];
  for (int k = 0; k < 128; k++) {
    float w = iw[k * 128 + tid];
#pragma unroll
    for (int r = 0; r < 11; r++) acc[r] += S[r * 128 + k] * w;
  }
#pragma unroll
  for (int r = 0; r < 11; r++) weff[r * 128 + tid] = acc[r];
  for (int idx = tid; idx < 512; idx += 128) {
    int pos = idx >> 4, d = idx & 15;
    float ang = (float)pos * expf(-0.57564627324851148f * (float)d);
    ropetab[idx] = cosf(ang);
    ropetab[512 + idx] = sinf(ang);
  }
}

// ============ 1. node embedding (collapsed linear form) ====================
__global__ __launch_bounds__(256) void node_embed2_kernel(
    const float* __restrict__ x, const float* __restrict__ weff,
    float* __restrict__ h) {
  __shared__ float XR[64 * XFv];
  __shared__ float RF[64][11];
  __shared__ __align__(16) float WE[11 * 128];
  int tid = threadIdx.x;
  int node0 = blockIdx.x * 64;
  for (int i = tid; i < 64 * XFv; i += 256)
    XR[i] = x[(size_t)node0 * XFv + i];
  for (int i = tid; i < 11 * 128; i += 256) WE[i] = weff[i];
  __syncthreads();
  {
    int nn = tid >> 2, sl = tid & 3;
    const float* xr = XR + nn * XFv;
    float p0 = xr[0], p1 = xr[1], p2 = xr[2];
    float g[6] = {0.f, 0.f, 0.f, 0.f, 0.f, 0.f};
#pragma unroll
    for (int s = 0; s < 6; s++) {
      const float* f = xr + 4 + 5 * (sl * 6 + s);
      float w = f[4];
      if (w != 0.0f) {
        g[0] += f[0]; g[1] += f[1] - p0; g[2] += f[2] - p1;
        g[3] += f[3] - p2; g[4] += w; g[5] += 1.0f;
      }
    }
#pragma unroll
    for (int i = 0; i < 6; i++) {
      g[i] += __shfl_xor(g[i], 1);
      g[i] += __shfl_xor(g[i], 2);
    }
    if (sl == 0) {
      RF[nn][0] = p0; RF[nn][1] = p1; RF[nn][2] = p2; RF[nn][3] = xr[3];
#pragma unroll
      for (int i = 0; i < 6; i++) RF[nn][4 + i] = g[i];
    }
  }
  __syncthreads();
  {
    int w = tid >> 6, lane = tid & 63;
    int c4 = lane & 31, hi = lane >> 5;
    const float4* WE4 = (const float4*)WE;
#pragma unroll
    for (int rr = 0; rr < 8; rr++) {
      int node = w * 16 + rr * 2 + hi;
      float4 acc = WE4[10 * 32 + c4];
#pragma unroll
      for (int f = 0; f < 10; f++)
        fma4(acc, RF[node][f], WE4[f * 32 + c4]);
      *(float4*)&h[(size_t)(node0 + node) * 128 + c4 * 4] = acc;
    }
  }
}

// ============================ 2. leaf dense ================================
__global__ __launch_bounds__(256) void leaf_dense_kernel(
    const float* __restrict__ h, const float* __restrict__ x,
    const float* __restrict__ lpw, const float* __restrict__ lpb,
    const float* __restrict__ lhw, const float* __restrict__ lhb,
    const float* __restrict__ lsc, float* __restrict__ out) {
  __shared__ __align__(16) float HS[32 * 128];
  __shared__ __align__(16) float HL[32 * 32];
  __shared__ __align__(16) float UL[32 * 32];
  int tid = threadIdx.x;
  int leaf = blockIdx.x;
  size_t base = (size_t)leaf * (32 * 128);
  for (int i = tid; i < 32 * 128; i += 256) {
    int t = i >> 7, c = i & 127;
    at1r(HS, t, c, 128) = h[base + i];
  }
  __syncthreads();
  int t = tid & 31, cg = tid >> 5;
  {
    float4 acc = ld4g(&lpb[4 * cg]);
    for (int k4 = 0; k4 < 128; k4 += 4) {
      float4 xv = *(const float4*)at4p(HS, t, k4, 128);
      float xa[4] = {xv.x, xv.y, xv.z, xv.w};
#pragma unroll
      for (int kk = 0; kk < 4; kk++)
        fma4(acc, xa[kk], ld4g(&lpw[(k4 + kk) * 32 + 4 * cg]));
    }
    *(float4*)at4p(HL, t, 4 * cg, 32) = acc;
  }
  __syncthreads();
  {
    float4 acc = ld4g(&lhb[4 * cg]);
    for (int k4 = 0; k4 < 32; k4 += 4) {
      float4 xv = *(const float4*)at4p(HL, t, k4, 32);
      float xa[4] = {xv.x, xv.y, xv.z, xv.w};
#pragma unroll
      for (int kk = 0; kk < 4; kk++)
        fma4(acc, xa[kk], ld4g(&lhw[(k4 + kk) * 32 + 4 * cg]));
    }
    *(float4*)at4p(UL, t, 4 * cg, 32) = acc;
  }
  __syncthreads();
  {
    float scale = expf(lsc[0]);
    float acc[4] = {0.f, 0.f, 0.f, 0.f};
    for (int k4 = 0; k4 < 32; k4 += 4) {
      float4 xv = *(const float4*)at4p(UL, t, k4, 32);
      float xa[4] = {xv.x, xv.y, xv.z, xv.w};
#pragma unroll
      for (int kk = 0; kk < 4; kk++) {
        int k = k4 + kk;
#pragma unroll
        for (int i2 = 0; i2 < 4; i2++)
          acc[i2] += xa[kk] * at1r(UL, 4 * cg + i2, k, 32);
      }
    }
    int b = leaf >> 8, l = leaf & 255;
#pragma unroll
    for (int i2 = 0; i2 < 4; i2++) {
      int c = 4 * cg + i2;
      float v = acc[i2] * scale;
      if (c == t) {
        float dg = x[(size_t)(leaf * 32 + t) * XFv + 3];
        v += (fabsf(dg) > 1e-6f) ? (1.0f / dg) : 1.0f;
      }
      out[(size_t)b * OPB + (size_t)l * 1024 + t * 32 + c] = v;
    }
  }
}

// ============ 3a. layer body (round-10 proven form, as device fn) ==========
DEV void layer_body(ushort* SM, int tid, int bid,
    float* __restrict__ h,
    const float* __restrict__ lng, const float* __restrict__ lnb,
    const ushort* __restrict__ wqkvt, const float* __restrict__ bqkv,
    const ushort* __restrict__ wpt, const float* __restrict__ pb,
    const float* __restrict__ rt,
    const float* __restrict__ ln2g, const float* __restrict__ ln2b,
    const ushort* __restrict__ w1t, const float* __restrict__ b1,
    const ushort* __restrict__ w2t, const float* __restrict__ b2) {
  ushort* XN = SM;            // R0 [0,8KB)
  ushort* QB = SM + 4096;     // R1 [8,16KB)
  ushort* KB = SM + 8192;     // R2 [16,24KB)
  ushort* VT = SM + 12288;    // R3 [24,32KB)
  ushort* HC1 = SM + 16384;   // R4 [32,40KB)
  float*  HS = (float*)(SM + 8192);   // fp32 32x128 over R2+R3
  size_t base = (size_t)bid * (32 * 128);
  int w = tid >> 6, l = tid & 63, lm = l & 15, q = l >> 4;

  { // --- A: LayerNorm1 -> bf16 XN ---
    int m8 = tid >> 3, p8 = tid & 7;
    const float* row = h + base + m8 * 128 + p8 * 16;
    float v[16];
    float s = 0.f;
#pragma unroll
    for (int i = 0; i < 16; i += 4) {
      float4 t4 = ld4g(row + i);
      v[i] = t4.x; v[i + 1] = t4.y; v[i + 2] = t4.z; v[i + 3] = t4.w;
      s += t4.x + t4.y + t4.z + t4.w;
    }
    s += __shfl_xor(s, 1); s += __shfl_xor(s, 2); s += __shfl_xor(s, 4);
    float mu = s * (1.0f / 128.0f);
    float s2 = 0.f;
#pragma unroll
    for (int i = 0; i < 16; i++) { float d = v[i] - mu; s2 += d * d; }
    s2 += __shfl_xor(s2, 1); s2 += __shfl_xor(s2, 2); s2 += __shfl_xor(s2, 4);
    float rs = rsqrtf(s2 * (1.0f / 128.0f) + 1e-5f);
    unsigned* XW = (unsigned*)XN;
#pragma unroll
    for (int i = 0; i < 16; i += 2) {
      int c = p8 * 16 + i;
      float x0 = (v[i] - mu) * rs * lng[c] + lnb[c];
      float x1 = (v[i + 1] - mu) * rs * lng[c + 1] + lnb[c + 1];
      int kp = c >> 1;
      XW[m8 * 64 + ((kp + 4 * m8) & 63)] = f2bf2(x0, x1);
    }
  }
  __syncthreads();

  { // --- B: qkv GEMM (M=32) + RoPE via table ---
    f32x4v acc[2][6];
#pragma unroll
    for (int mt = 0; mt < 2; mt++)
#pragma unroll
      for (int nt = 0; nt < 6; nt++) acc[mt][nt] = (f32x4v){0.f, 0.f, 0.f, 0.f};
    for (int ks = 0; ks < 4; ks++) {
      bfrag a[2];
#pragma unroll
      for (int mt = 0; mt < 2; mt++) {
        int mm = mt * 16 + lm;
        a[mt] = *(const bfrag*)&XN[mm * 128 + ((ks * 32 + q * 8 + 8 * mm) & 127)];
      }
#pragma unroll
      for (int nt = 0; nt < 6; nt++) {
        int n = w * 96 + nt * 16 + lm;
        bfrag b = *(const bfrag*)&wqkvt[(size_t)n * 128 + ks * 32 + q * 8];
#pragma unroll
        for (int mt = 0; mt < 2; mt++)
          acc[mt][nt] = __builtin_amdgcn_mfma_f32_16x16x32_bf16(
              a[mt], b, acc[mt][nt], 0, 0, 0);
      }
    }
    float csA[4] = {}, snA[4] = {}, csB[4] = {}, snB[4] = {};
    if (w < 3) {   // only q/k waves rotate
#pragma unroll
      for (int r = 0; r < 4; r++) {
        int pa = q * 4 + r;
        csA[r] = rt[pa * 16 + lm];        snA[r] = rt[512 + pa * 16 + lm];
        csB[r] = rt[(pa + 16) * 16 + lm]; snB[r] = rt[512 + (pa + 16) * 16 + lm];
      }
    }
#pragma unroll
    for (int p2 = 0; p2 < 3; p2++) {
      int g = w * 6 + 2 * p2;
      int ne = g * 16 + lm;
      if (g < 16) {
        float be = bqkv[ne], bo = bqkv[ne + 16];
        ushort* dst = (g < 8) ? QB : KB;
        int de = (g < 8) ? ne : ne - 128;
#pragma unroll
        for (int mt = 0; mt < 2; mt++)
#pragma unroll
          for (int r = 0; r < 4; r++) {
            int mm = mt * 16 + q * 4 + r;
            float cs = (mt & 1) ? csB[r] : csA[r];
            float sn = (mt & 1) ? snB[r] : snA[r];
            float e = acc[mt][2 * p2][r] + be;
            float o = acc[mt][2 * p2 + 1][r] + bo;
            stb128(dst, mm, de, e * cs - o * sn);
            stb128(dst, mm, de + 16, o * cs + e * sn);
          }
      } else {
#pragma unroll
        for (int h2 = 0; h2 < 2; h2++) {
          int nt = 2 * p2 + h2;
          int nv = (g + h2) * 16 + lm;
          int dv = nv - 256;
          float bv = bqkv[nv];
#pragma unroll
          for (int mt = 0; mt < 2; mt++) {
            int t0 = mt * 16 + q * 4;
            uint2 pk;
            pk.x = f2bf2(acc[mt][nt][0] + bv, acc[mt][nt][1] + bv);
            pk.y = f2bf2(acc[mt][nt][2] + bv, acc[mt][nt][3] + bv);
            *(uint2*)&VT[dv * 32 + (((t0 & ~7) + 8 * dv) & 31) + (t0 & 7)] = pk;
          }
        }
      }
    }
  }
  __syncthreads();

  ushort* SP = XN;   // scores overlay XN (dead after B)
  ushort* OB = QB;   // attn-out overlays QB (dead after C)
  { // --- C+D+E: wave-private attention core for head w (no barriers) ---
    int head = w;
    { // C: scores
      f32x4v sc[2][2];
#pragma unroll
      for (int a2 = 0; a2 < 2; a2++)
#pragma unroll
        for (int b2 = 0; b2 < 2; b2++) sc[a2][b2] = (f32x4v){0.f, 0.f, 0.f, 0.f};
      bfrag qa[2], kb[2];
#pragma unroll
      for (int mt2 = 0; mt2 < 2; mt2++) {
        int row = mt2 * 16 + lm;
        qa[mt2] = *(const bfrag*)&QB[row * 128 + ((head * 32 + q * 8 + 8 * row) & 127)];
      }
#pragma unroll
      for (int nt2 = 0; nt2 < 2; nt2++) {
        int kt = nt2 * 16 + lm;
        kb[nt2] = *(const bfrag*)&KB[kt * 128 + ((head * 32 + q * 8 + 8 * kt) & 127)];
      }
#pragma unroll
      for (int mt2 = 0; mt2 < 2; mt2++)
#pragma unroll
        for (int nt2 = 0; nt2 < 2; nt2++)
          sc[mt2][nt2] = __builtin_amdgcn_mfma_f32_16x16x32_bf16(
              qa[mt2], kb[nt2], sc[mt2][nt2], 0, 0, 0);
      const float scl = 0.17677669529663688f;
#pragma unroll
      for (int mt2 = 0; mt2 < 2; mt2++)
#pragma unroll
        for (int nt2 = 0; nt2 < 2; nt2++)
#pragma unroll
          for (int r = 0; r < 4; r++) {
            int qt = mt2 * 16 + q * 4 + r;
            int kc = nt2 * 16 + lm;
            SP[head * 1024 + qt * 32 + (((kc & ~7) + 8 * qt) & 31) + (kc & 7)] =
                f2bf(sc[mt2][nt2][r] * scl);
          }
    }
    { // D: softmax (wave-local: 64 lanes over 32 rows, 2 lanes/row)
      int rowid = l >> 1, half = l & 1;
      ushort* rowp = SP + head * 1024 + rowid * 32 + half * 16;
      float v[16];
#pragma unroll
      for (int pc = 0; pc < 2; pc++) {
        uint4 ch = *(const uint4*)&rowp[pc * 8];
        unsigned uu[4] = {ch.x, ch.y, ch.z, ch.w};
#pragma unroll
        for (int i2 = 0; i2 < 4; i2++) {
          v[pc * 8 + 2 * i2]     = __uint_as_float(uu[i2] << 16);
          v[pc * 8 + 2 * i2 + 1] = __uint_as_float(uu[i2] & 0xffff0000u);
        }
      }
      float mx = -1e30f;
#pragma unroll
      for (int i = 0; i < 16; i++) mx = fmaxf(mx, v[i]);
      mx = fmaxf(mx, __shfl_xor(mx, 1));
      float s = 0.f;
#pragma unroll
      for (int i = 0; i < 16; i++) { v[i] = __expf(v[i] - mx); s += v[i]; }
      s += __shfl_xor(s, 1);
      float inv = 1.0f / s;
#pragma unroll
      for (int pc = 0; pc < 2; pc++) {
        uint4 ch;
        unsigned uu[4];
#pragma unroll
        for (int i2 = 0; i2 < 4; i2++)
          uu[i2] = f2bf2(v[pc * 8 + 2 * i2] * inv, v[pc * 8 + 2 * i2 + 1] * inv);
        ch.x = uu[0]; ch.y = uu[1]; ch.z = uu[2]; ch.w = uu[3];
        *(uint4*)&rowp[pc * 8] = ch;
      }
    }
    { // E: O = P @ V
      f32x4v ov[2][2];
#pragma unroll
      for (int a2 = 0; a2 < 2; a2++)
#pragma unroll
        for (int b2 = 0; b2 < 2; b2++) ov[a2][b2] = (f32x4v){0.f, 0.f, 0.f, 0.f};
      bfrag pa[2], vb2[2];
#pragma unroll
      for (int mt2 = 0; mt2 < 2; mt2++) {
        int qt = mt2 * 16 + lm;
        pa[mt2] = *(const bfrag*)&SP[head * 1024 + qt * 32 + ((q * 8 + 8 * qt) & 31)];
      }
#pragma unroll
      for (int nt2 = 0; nt2 < 2; nt2++) {
        int gdim = head * 32 + nt2 * 16 + lm;
        vb2[nt2] = *(const bfrag*)&VT[gdim * 32 + ((q * 8 + 8 * gdim) & 31)];
      }
#pragma unroll
      for (int mt2 = 0; mt2 < 2; mt2++)
#pragma unroll
        for (int nt2 = 0; nt2 < 2; nt2++)
          ov[mt2][nt2] = __builtin_amdgcn_mfma_f32_16x16x32_bf16(
              pa[mt2], vb2[nt2], ov[mt2][nt2], 0, 0, 0);
#pragma unroll
      for (int mt2 = 0; mt2 < 2; mt2++)
#pragma unroll
        for (int nt2 = 0; nt2 < 2; nt2++)
#pragma unroll
          for (int r = 0; r < 4; r++) {
            int qt = mt2 * 16 + q * 4 + r;
            int gdim = head * 32 + nt2 * 16 + lm;
            stb128(OB, qt, gdim, ov[mt2][nt2][r]);
          }
    }
  }
  __syncthreads();

  { // --- F: out-proj -> HS = attn_out + pb (fp32, 4-rotated rows) ---
    f32x4v po[2][2];
#pragma unroll
    for (int mt = 0; mt < 2; mt++)
#pragma unroll
      for (int nt = 0; nt < 2; nt++) po[mt][nt] = (f32x4v){0.f, 0.f, 0.f, 0.f};
    for (int ks = 0; ks < 4; ks++) {
      bfrag a[2];
#pragma unroll
      for (int mt = 0; mt < 2; mt++) {
        int mm = mt * 16 + lm;
        a[mt] = *(const bfrag*)&OB[mm * 128 + ((ks * 32 + q * 8 + 8 * mm) & 127)];
      }
#pragma unroll
      for (int nt = 0; nt < 2; nt++) {
        int n = w * 32 + nt * 16 + lm;
        bfrag b = *(const bfrag*)&wpt[(size_t)n * 128 + ks * 32 + q * 8];
#pragma unroll
        for (int mt = 0; mt < 2; mt++)
          po[mt][nt] = __builtin_amdgcn_mfma_f32_16x16x32_bf16(
              a[mt], b, po[mt][nt], 0, 0, 0);
      }
    }
#pragma unroll
    for (int nt = 0; nt < 2; nt++) {
      int n = w * 32 + nt * 16 + lm;
      float bv = pb[n];
#pragma unroll
      for (int mt = 0; mt < 2; mt++)
#pragma unroll
        for (int r = 0; r < 4; r++) {
          int mm = mt * 16 + q * 4 + r;
          at1r(HS, mm, n, 128) = po[mt][nt][r] + bv;
        }
    }
  }
  __syncthreads();

  { // --- G: hn = h + attn_out (in HS); LayerNorm2 -> bf16 XN2 ---
    int j = tid & 31;
    int c0 = j * 4;
    float g0 = ln2g[c0], g1 = ln2g[c0 + 1], g2 = ln2g[c0 + 2], g3 = ln2g[c0 + 3];
    float e0 = ln2b[c0], e1 = ln2b[c0 + 1], e2 = ln2b[c0 + 2], e3 = ln2b[c0 + 3];
    unsigned* XW = (unsigned*)XN;
#pragma unroll
    for (int k2 = 0; k2 < 4; k2++) {
      int idx = tid + 256 * k2;
      int tok = idx >> 5;
      float4 hg = ld4g(&h[base + (size_t)idx * 4]);
      float4 ao = *(const float4*)at4p(HS, tok, 4 * j, 128);
      float4 hn;
      hn.x = hg.x + ao.x; hn.y = hg.y + ao.y;
      hn.z = hg.z + ao.z; hn.w = hg.w + ao.w;
      *(float4*)at4p(HS, tok, 4 * j, 128) = hn;
      float s = hn.x + hn.y + hn.z + hn.w;
      s += __shfl_xor(s, 1); s += __shfl_xor(s, 2); s += __shfl_xor(s, 4);
      s += __shfl_xor(s, 8); s += __shfl_xor(s, 16);
      float mu = s * (1.0f / 128.0f);
      float d0 = hn.x - mu, d1 = hn.y - mu, d2 = hn.z - mu, d3 = hn.w - mu;
      float s2 = d0 * d0 + d1 * d1 + d2 * d2 + d3 * d3;
      s2 += __shfl_xor(s2, 1); s2 += __shfl_xor(s2, 2); s2 += __shfl_xor(s2, 4);
      s2 += __shfl_xor(s2, 8); s2 += __shfl_xor(s2, 16);
      float rs = rsqrtf(s2 * (1.0f / 128.0f) + 1e-5f);
      float x0 = d0 * rs * g0 + e0;
      float x1 = d1 * rs * g1 + e1;
      float x2 = d2 * rs * g2 + e2;
      float x3 = d3 * rs * g3 + e3;
      int kp = 2 * j;
      XW[tok * 64 + ((kp + 4 * tok) & 63)] = f2bf2(x0, x1);
      XW[tok * 64 + ((kp + 1 + 4 * tok) & 63)] = f2bf2(x2, x3);
    }
  }
  __syncthreads();

  // --- mlp: 4 hidden chunks, double-buffered HC, 1 barrier/chunk ---
  ushort* HC0 = QB;
  f32x4v acc2[2][2];
#pragma unroll
  for (int mt = 0; mt < 2; mt++)
#pragma unroll
    for (int nt = 0; nt < 2; nt++) acc2[mt][nt] = (f32x4v){0.f, 0.f, 0.f, 0.f};

  auto mlp1_calc = [&](int hc, f32x4v A1[2][2]) {
#pragma unroll
    for (int mt = 0; mt < 2; mt++)
#pragma unroll
      for (int nt = 0; nt < 2; nt++) A1[mt][nt] = (f32x4v){0.f, 0.f, 0.f, 0.f};
#pragma unroll
    for (int ks = 0; ks < 4; ks++) {
      bfrag a[2];
#pragma unroll
      for (int mt = 0; mt < 2; mt++) {
        int mm = mt * 16 + lm;
        a[mt] = *(const bfrag*)&XN[mm * 128 + ((ks * 32 + q * 8 + 8 * mm) & 127)];
      }
#pragma unroll
      for (int nt = 0; nt < 2; nt++) {
        int n = hc * 128 + w * 32 + nt * 16 + lm;
        bfrag b = *(const bfrag*)&w1t[(size_t)n * 128 + ks * 32 + q * 8];
#pragma unroll
        for (int mt = 0; mt < 2; mt++)
          A1[mt][nt] = __builtin_amdgcn_mfma_f32_16x16x32_bf16(
              a[mt], b, A1[mt][nt], 0, 0, 0);
      }
    }
  };
  auto gelu_store = [&](int hc, f32x4v A1[2][2], ushort* HCd) {
#pragma unroll
    for (int nt = 0; nt < 2; nt++) {
      int nl = w * 32 + nt * 16 + lm;
      float b1v = b1[hc * 128 + nl];
#pragma unroll
      for (int mt = 0; mt < 2; mt++)
#pragma unroll
        for (int r = 0; r < 4; r++) {
          int mm = mt * 16 + q * 4 + r;
          float val = gelu_fast(A1[mt][nt][r] + b1v);
          HCd[mm * 128 + (((nl & ~7) + 8 * mm) & 127) + (nl & 7)] = f2bf(val);
        }
    }
  };
  auto mlp2_calc = [&](int hc, ushort* HCr) {
#pragma unroll
    for (int ks = 0; ks < 4; ks++) {
      bfrag a[2];
#pragma unroll
      for (int mt = 0; mt < 2; mt++) {
        int mm = mt * 16 + lm;
        a[mt] = *(const bfrag*)&HCr[mm * 128 + ((ks * 32 + q * 8 + 8 * mm) & 127)];
      }
#pragma unroll
      for (int nt = 0; nt < 2; nt++) {
        int n = w * 32 + nt * 16 + lm;
        bfrag b = *(const bfrag*)&w2t[(size_t)n * 512 + hc * 128 + ks * 32 + q * 8];
#pragma unroll
        for (int mt = 0; mt < 2; mt++)
          acc2[mt][nt] = __builtin_amdgcn_mfma_f32_16x16x32_bf16(
              a[mt], b, acc2[mt][nt], 0, 0, 0);
      }
    }
  };

  f32x4v a1A[2][2], a1B[2][2];
  mlp1_calc(0, a1A);
  gelu_store(0, a1A, HC0);
  __syncthreads();
  mlp1_calc(1, a1B);
  mlp2_calc(0, HC0);
  gelu_store(1, a1B, HC1);
  __syncthreads();
  mlp1_calc(2, a1A);
  mlp2_calc(1, HC1);
  gelu_store(2, a1A, HC0);
  __syncthreads();
  mlp1_calc(3, a1B);
  mlp2_calc(2, HC0);
  gelu_store(3, a1B, HC1);
  __syncthreads();
  mlp2_calc(3, HC1);

  // --- epilogue: h = hn (HS) + mlp_out + b2 — the ONLY global h write ---
#pragma unroll
  for (int nt = 0; nt < 2; nt++) {
    int n = w * 32 + nt * 16 + lm;
    float b2v = b2[n];
#pragma unroll
    for (int mt = 0; mt < 2; mt++)
#pragma unroll
      for (int r = 0; r < 4; r++) {
        int mm = mt * 16 + q * 4 + r;
        h[base + (size_t)mm * 128 + n] = at1r(HS, mm, n, 128) + acc2[mt][nt][r] + b2v;
      }
  }
}

// ============ 3b. uv body (64-token tiles -> compact staging) ==============
template <int EXPJ, int RANK, int NSPLIT>
DEV void uv_body(ushort* XN, int tid, int ubid, int nx,
    const float* __restrict__ h,
    const ushort* __restrict__ uwt, const float* __restrict__ ub,
    const ushort* __restrict__ vwt, const float* __restrict__ vb,
    float* __restrict__ ustg, float* __restrict__ vstg) {
  constexpr int NT16 = (EXPJ + 15) / 16;
  constexpr int NJOBS = 2 * NT16;
  int bx = ubid % nx, by = ubid / nx;
  int t0 = bx * 64;
  size_t base = (size_t)t0 * 128;
  {
    int m = tid >> 2, p = tid & 3;
    const float* row = h + base + m * 128 + p * 32;
    unsigned* XW = (unsigned*)XN;
#pragma unroll
    for (int i = 0; i < 32; i += 4) {
      float4 t4 = ld4g(row + i);
      int kp = (p * 32 + i) >> 1;
      XW[m * 64 + ((kp + 4 * m) & 63)] = f2bf2(t4.x, t4.y);
      XW[m * 64 + ((kp + 1 + 4 * m) & 63)] = f2bf2(t4.z, t4.w);
    }
  }
  __syncthreads();
  int w = tid >> 6, l = tid & 63, lm = l & 15, q = l >> 4;
  int gw = w + 4 * by;
  for (int jj = gw; jj < NJOBS; jj += 4 * NSPLIT) {
    int uvsel = jj & 1, nt = jj >> 1;
    const ushort* wt = uvsel ? vwt : uwt;
    const float* bias = uvsel ? vb : ub;
    float* stg = uvsel ? vstg : ustg;
    f32x4v acc[4];
#pragma unroll
    for (int mt = 0; mt < 4; mt++) acc[mt] = (f32x4v){0.f, 0.f, 0.f, 0.f};
    for (int ks = 0; ks < 4; ks++) {
      bfrag b = *(const bfrag*)&wt[(size_t)(nt * 16 + lm) * 128 + ks * 32 + q * 8];
#pragma unroll
      for (int mt = 0; mt < 4; mt++) {
        int mm = mt * 16 + lm;
        int ke = ks * 32 + q * 8;
        bfrag a = *(const bfrag*)&XN[mm * 128 + ((ke + 8 * mm) & 127)];
        acc[mt] = __builtin_amdgcn_mfma_f32_16x16x32_bf16(a, b, acc[mt], 0, 0, 0);
      }
    }
    int c = nt * 16 + lm;
    if (c < EXPJ) {
      float bv = bias[c];
#pragma unroll
      for (int mt = 0; mt < 4; mt++)
#pragma unroll
        for (int r = 0; r < 4; r++) {
          int mm = mt * 16 + q * 4 + r;
          stg[(size_t)(t0 + mm) * EXPJ + c] = acc[mt][r] + bv;
        }
    }
  }
}

// ====== 3c. standalone layer (level 0) =====================================
__global__ __launch_bounds__(256, 4) void layer_mfma_kernel(
    float* __restrict__ h,
    const float* __restrict__ lng, const float* __restrict__ lnb,
    const ushort* __restrict__ wqkvt, const float* __restrict__ bqkv,
    const ushort* __restrict__ wpt, const float* __restrict__ pb,
    const float* __restrict__ rt,
    const float* __restrict__ ln2g, const float* __restrict__ ln2b,
    const ushort* __restrict__ w1t, const float* __restrict__ b1,
    const ushort* __restrict__ w2t, const float* __restrict__ b2) {
  __shared__ __align__(16) ushort SM[20480];
  layer_body(SM, threadIdx.x, blockIdx.x, h, lng, lnb, wqkvt, bqkv, wpt, pb,
             rt, ln2g, ln2b, w1t, b1, w2t, b2);
}

// ====== 3d. combo: layer level j+1 (blocks < nLayer) + uv level j ==========
template <int EXPJ, int RANK, int NSPLIT>
__global__ __launch_bounds__(256, 4) void combo_kernel(
    float* __restrict__ h,
    const float* __restrict__ lng, const float* __restrict__ lnb,
    const ushort* __restrict__ wqkvt, const float* __restrict__ bqkv,
    const ushort* __restrict__ wpt, const float* __restrict__ pb,
    const float* __restrict__ rt,
    const float* __restrict__ ln2g, const float* __restrict__ ln2b,
    const ushort* __restrict__ w1t, const float* __restrict__ b1,
    const ushort* __restrict__ w2t, const float* __restrict__ b2,
    int nLayer,
    const float* __restrict__ hprev,
    const ushort* __restrict__ uwt, const float* __restrict__ ub,
    const ushort* __restrict__ vwt, const float* __restrict__ vb,
    float* __restrict__ ustg, float* __restrict__ vstg, int nx) {
  __shared__ __align__(16) ushort SM[20480];
  int tid = threadIdx.x;
  if ((int)blockIdx.x < nLayer) {
    layer_body(SM, tid, blockIdx.x, h, lng, lnb, wqkvt, bqkv, wpt, pb,
               rt, ln2g, ln2b, w1t, b1, w2t, b2);
  } else {
    uv_body<EXPJ, RANK, NSPLIT>(SM, tid, (int)blockIdx.x - nLayer, nx,
                                hprev, uwt, ub, vwt, vb, ustg, vstg);
  }
}

// ====== 3e. standalone uv (level 3) ========================================
template <int EXPJ, int RANK, int NSPLIT>
__global__ __launch_bounds__(256, 4) void uv_kernel(
    const float* __restrict__ h,
    const ushort* __restrict__ uwt, const float* __restrict__ ub,
    const ushort* __restrict__ vwt, const float* __restrict__ vb,
    float* __restrict__ ustg, float* __restrict__ vstg, int nx) {
  __shared__ __align__(16) ushort XN[64 * 128];
  uv_body<EXPJ, RANK, NSPLIT>(XN, threadIdx.x, blockIdx.x, nx,
                              h, uwt, ub, vwt, vb, ustg, vstg);
}

// ====== 4. downsample (critical path: h_j -> h_{j+1}) ======================
__global__ __launch_bounds__(256) void ds_kernel(
    const float* __restrict__ h, float* __restrict__ hout,
    const ushort* __restrict__ dwt, const float* __restrict__ dsb) {
  __shared__ __align__(16) ushort XN[64 * 128];
  int tid = threadIdx.x;
  int t0 = blockIdx.x * 64;
  size_t base = (size_t)t0 * 128;
  {
    int m = tid >> 2, p = tid & 3;
    const float* row = h + base + m * 128 + p * 32;
    unsigned* XW = (unsigned*)XN;
#pragma unroll
    for (int i = 0; i < 32; i += 4) {
      float4 t4 = ld4g(row + i);
      int kp = (p * 32 + i) >> 1;
      XW[m * 64 + ((kp + 4 * m) & 63)] = f2bf2(t4.x, t4.y);
      XW[m * 64 + ((kp + 1 + 4 * m) & 63)] = f2bf2(t4.z, t4.w);
    }
  }
  __syncthreads();
  int w = tid >> 6, l = tid & 63, lm = l & 15, q = l >> 4;
  f32x4v dacc[2][2];
#pragma unroll
  for (int mt = 0; mt < 2; mt++)
#pragma unroll
    for (int nt = 0; nt < 2; nt++) dacc[mt][nt] = (f32x4v){0.f, 0.f, 0.f, 0.f};
  for (int ks = 0; ks < 8; ks++) {
    bfrag a[2];
#pragma unroll
    for (int mt = 0; mt < 2; mt++) {
      int rr = mt * 16 + lm;
      int tok = 2 * rr + (ks >> 2);
      int c2 = (ks & 3) * 32 + q * 8;
      a[mt] = *(const bfrag*)&XN[tok * 128 + ((c2 + 8 * tok) & 127)];
    }
#pragma unroll
    for (int nt = 0; nt < 2; nt++) {
      int n = w * 32 + nt * 16 + lm;
      bfrag b = *(const bfrag*)&dwt[(size_t)n * 256 + ks * 32 + q * 8];
#pragma unroll
      for (int mt = 0; mt < 2; mt++)
        dacc[mt][nt] = __builtin_amdgcn_mfma_f32_16x16x32_bf16(
            a[mt], b, dacc[mt][nt], 0, 0, 0);
    }
  }
  size_t ob2 = (size_t)blockIdx.x * (32 * 128);
#pragma unroll
  for (int nt = 0; nt < 2; nt++) {
    int n = w * 32 + nt * 16 + lm;
    float bv = dsb[n];
#pragma unroll
    for (int mt = 0; mt < 2; mt++)
#pragma unroll
      for (int r = 0; r < 4; r++) {
        int mm = mt * 16 + q * 4 + r;
        hout[ob2 + (size_t)mm * 128 + n] = dacc[mt][nt][r] + bv;
      }
  }
}

// ====== 6. final uv assembly: staging -> out rows, fully contiguous ========
struct StgPtrs { const float* u[4]; const float* v[4]; };
__global__ __launch_bounds__(256) void uv_assemble_kernel(
    StgPtrs sp, float* __restrict__ out) {
  __shared__ unsigned char JL[93];
  __shared__ unsigned char CM[93];
  int tid = threadIdx.x;
  if (tid < 93) {
    int c = 2 * tid;
    int j = (c < 20) ? 0 : (c < 52) ? 1 : (c < 104) ? 2 : 3;
    int coff = (j == 0) ? 0 : (j == 1) ? 20 : (j == 2) ? 52 : 104;
    JL[tid] = (unsigned char)j;
    CM[tid] = (unsigned char)(c - coff);
  }
  __syncthreads();
  int g0 = blockIdx.x * 32;   // 32 global node-rows per block
  for (int i = tid; i < 32 * 93; i += 256) {
    int rr = i / 93, cp = i - rr * 93;
    int g = g0 + rr;
    int b = g >> 13, n = g & 8191;
    int j = JL[cp], cm = CM[cp];
    int expj, rank;
    if (j == 0)      { expj = 20;  rank = 20; }
    else if (j == 1) { expj = 64;  rank = 32; }
    else if (j == 2) { expj = 208; rank = 52; }
    else             { expj = 656; rank = 82; }
    int tok = (b << (13 - j)) + (n >> j);
    int cdiv = n & ((1 << j) - 1);
    size_t si = (size_t)tok * expj + cdiv * rank + cm;
    size_t ob = (size_t)b * OPB + (size_t)n * UVWID + 2 * cp;
    *(float2*)&out[ob + UBASE] = *(const float2*)&sp.u[j][si];
    *(float2*)&out[ob + VBASE] = *(const float2*)&sp.v[j][si];
  }
}

// ================================ host =====================================
extern "C" void kernel_launch(void* const* d_in, const int* in_sizes, int n_in,
                              void* d_out, int out_size, void* d_ws, size_t ws_size,
                              hipStream_t stream) {
  const float* x       = (const float*)d_in[0];
  const float* cen_w   = (const float*)d_in[1];
  const float* cen_b   = (const float*)d_in[2];
  const float* nbr_w   = (const float*)d_in[3];
  const float* nbr_b   = (const float*)d_in[4];
  const float* inp_w   = (const float*)d_in[5];
  const float* inp_b   = (const float*)d_in[6];
  const float* leafp_w = (const float*)d_in[7];
  const float* leafp_b = (const float*)d_in[8];
  const float* leafh_w = (const float*)d_in[9];
  const float* leafh_b = (const float*)d_in[10];
  const float* lscale  = (const float*)d_in[11];
  const float* ln1_g   = (const float*)d_in[12];
  const float* ln1_b   = (const float*)d_in[13];
  const float* qkv_w   = (const float*)d_in[14];
  const float* qkv_b   = (const float*)d_in[15];
  const float* attnp_w = (const float*)d_in[16];
  const float* attnp_b = (const float*)d_in[17];
  const float* ln2_g   = (const float*)d_in[18];
  const float* ln2_b   = (const float*)d_in[19];
  const float* mlp1_w  = (const float*)d_in[20];
  const float* mlp1_b  = (const float*)d_in[21];
  const float* mlp2_w  = (const float*)d_in[22];
  const float* mlp2_b  = (const float*)d_in[23];
  const float* ds_w    = (const float*)d_in[24];
  const float* ds_b    = (const float*)d_in[25];
  const float* huw[4], *hub[4], *hvw[4], *hvb[4];
  for (int j = 0; j < 4; j++) {
    huw[j] = (const float*)d_in[26 + 4 * j];
    hub[j] = (const float*)d_in[27 + 4 * j];
    hvw[j] = (const float*)d_in[28 + 4 * j];
    hvb[j] = (const float*)d_in[29 + 4 * j];
  }
  float* out = (float*)d_out;
  float* hA = (float*)d_ws;                       // 4*8192*128 fp32 = 16 MB
  float* hB = hA + (size_t)4 * 8192 * 128;        // 8 MB (ping-pong)
  ushort* w1t = (ushort*)(hB + (size_t)2097152);
  ushort* w2t = w1t + (size_t)4 * 65536;
  ushort* uvt = w2t + (size_t)4 * 65536;
  const int NPAD[4] = {32, 64, 208, 656};
  ushort* uwt[4]; ushort* vwt[4];
  ushort* p = uvt;
  for (int j = 0; j < 4; j++) {
    uwt[j] = p; p += (size_t)NPAD[j] * 128;
    vwt[j] = p; p += (size_t)NPAD[j] * 128;
  }
  ushort* wqkvt = p;                              // 4 levels x 384x128 bf16
  ushort* wpt   = wqkvt + (size_t)4 * 384 * 128;  // 4 levels x 128x128 bf16
  ushort* dswt  = wpt + (size_t)4 * 128 * 128;    // 4 levels x 128x256 bf16
  float* weff   = (float*)(dswt + (size_t)4 * 128 * 256);   // 11 x 128 fp32
  float* ropetab = weff + 1408;                   // 1024 floats
  // uv staging: [global_token][EXPJ] fp32 per level (u and v)
  const size_t STG[4] = {32768ull * 20, 16384ull * 64, 8192ull * 208, 4096ull * 656};
  float* ustg[4]; float* vstg[4];
  float* sp2 = ropetab + 1024;
  for (int j = 0; j < 4; j++) {
    ustg[j] = sp2; sp2 += STG[j];
    vstg[j] = sp2; sp2 += STG[j];
  }
  const int EXPJ_[4] = {20, 64, 208, 656};

  // stage 0: weight prep
  weff_prep_kernel<<<1, 128, 0, stream>>>(
      cen_w, cen_b, nbr_w, nbr_b, inp_w, inp_b, weff, ropetab);
  wprep_all_kernel<<<dim3(2, 8, 4), 256, 0, stream>>>(mlp1_w, w1t, 128, 512);
  wprep_all_kernel<<<dim3(8, 2, 4), 256, 0, stream>>>(mlp2_w, w2t, 512, 128);
  wprep_all_kernel<<<dim3(2, 6, 4), 256, 0, stream>>>(qkv_w, wqkvt, 128, 384);
  wprep_all_kernel<<<dim3(2, 2, 4), 256, 0, stream>>>(attnp_w, wpt, 128, 128);
  wprep_all_kernel<<<dim3(4, 2, 4), 256, 0, stream>>>(ds_w, dswt, 256, 128);
  {
    UVDesc d;
    for (int j = 0; j < 4; j++) {
      d.src[2 * j] = huw[j];     d.dst[2 * j] = uwt[j];
      d.src[2 * j + 1] = hvw[j]; d.dst[2 * j + 1] = vwt[j];
      d.expj[2 * j] = EXPJ_[j];  d.expj[2 * j + 1] = EXPJ_[j];
      d.npad[2 * j] = NPAD[j];   d.npad[2 * j + 1] = NPAD[j];
    }
    uvprep_all_kernel<<<dim3(328, 8), 256, 0, stream>>>(d);
  }

  // stage 1: node embedding -> hA
  node_embed2_kernel<<<(4 * 8192) / 64, 256, 0, stream>>>(x, weff, hA);
  // stage 2: leaf dense Gram
  leaf_dense_kernel<<<(4 * 8192) / 32, 256, 0, stream>>>(
      hA, x, leafp_w, leafp_b, leafh_w, leafh_b, lscale, out);

  // stage 3: layer0 -> ds0 -> [layer1||uv0] -> ds1 -> [layer2||uv1]
  //          -> ds2 -> [layer3||uv2] -> uv3 -> assemble
  layer_mfma_kernel<<<32768 / 32, 256, 0, stream>>>(
      hA, ln1_g, ln1_b, wqkvt, qkv_b, wpt, attnp_b, ropetab,
      ln2_g, ln2_b, w1t, mlp1_b, w2t, mlp2_b);
  ds_kernel<<<512, 256, 0, stream>>>(hA, hB, dswt, ds_b);

  combo_kernel<20, 20, 1><<<512 + 512, 256, 0, stream>>>(
      hB, ln1_g + 128, ln1_b + 128, wqkvt + 49152, qkv_b + 384,
      wpt + 16384, attnp_b + 128, ropetab,
      ln2_g + 128, ln2_b + 128, w1t + 65536, mlp1_b + 512,
      w2t + 65536, mlp2_b + 128, 512,
      hA, uwt[0], hub[0], vwt[0], hvb[0], ustg[0], vstg[0], 512);
  ds_kernel<<<256, 256, 0, stream>>>(hB, hA, dswt + 32768, ds_b + 128);

  combo_kernel<64, 32, 2><<<256 + 512, 256, 0, stream>>>(
      hA, ln1_g + 256, ln1_b + 256, wqkvt + 98304, qkv_b + 768,
      wpt + 32768, attnp_b + 256, ropetab,
      ln2_g + 256, ln2_b + 256, w1t + 131072, mlp1_b + 1024,
      w2t + 131072, mlp2_b + 256, 256,
      hB, uwt[1], hub[1], vwt[1], hvb[1], ustg[1], vstg[1], 256);
  ds_kernel<<<128, 256, 0, stream>>>(hA, hB, dswt + 65536, ds_b + 256);

  combo_kernel<208, 52, 4><<<128 + 512, 256, 0, stream>>>(
      hB, ln1_g + 384, ln1_b + 384, wqkvt + 147456, qkv_b + 1152,
      wpt + 49152, attnp_b + 384, ropetab,
      ln2_g + 384, ln2_b + 384, w1t + 196608, mlp1_b + 1536,
      w2t + 196608, mlp2_b + 384, 128,
      hA, uwt[2], hub[2], vwt[2], hvb[2], ustg[2], vstg[2], 128);

  uv_kernel<656, 82, 8><<<512, 256, 0, stream>>>(
      hB, uwt[3], hub[3], vwt[3], hvb[3], ustg[3], vstg[3], 64);

  // final: assemble uv rows contiguously
  {
    StgPtrs sp;
    for (int j = 0; j < 4; j++) { sp.u[j] = ustg[j]; sp.v[j] = vstg[j]; }
    uv_assemble_kernel<<<32768 / 32, 256, 0, stream>>>(sp, out);
  }
  (void)in_sizes; (void)n_in; (void)out_size; (void)ws_size;
}

// Round 12
// 417.113 us; speedup vs baseline: 1.4110x; 1.4110x over previous
//
#include <hip/hip_runtime.h>
#include <hip/hip_bf16.h>
#include <math.h>

#define DEV __device__ __forceinline__

constexpr int XFv = 124;              // features per node row
constexpr size_t OPB   = 3309568;     // output floats per batch
constexpr size_t UBASE = 262144;      // dense floats per batch
constexpr size_t VBASE = 1785856;     // UBASE + 8192*186
constexpr int UVWID = 186;            // 20+32+52+82

using bfrag  = __attribute__((ext_vector_type(8))) short;   // 8 bf16
using f32x4v = __attribute__((ext_vector_type(4))) float;   // MFMA acc

// --- rotated LDS layout helpers (fp32 tiles) ---
DEV float* at4p(float* base, int t, int c0, int W) {
  return base + t * W + ((c0 + 4 * t) & (W - 1));
}
DEV float& at1r(float* base, int t, int c, int W) {
  return base[t * W + (((c & ~3) + 4 * t) & (W - 1)) + (c & 3)];
}
DEV float4 ld4g(const float* p) { return *(const float4*)p; }
DEV void fma4(float4& a, float s, const float4& w) {
  a.x += s * w.x; a.y += s * w.y; a.z += s * w.z; a.w += s * w.w;
}
// tanh-form GELU: gelu(x) ~= x * e/(e+1), e = exp(x*(c1 + c2*x^2)).
DEV float gelu_fast(float x) {
  float x2 = x * x;
  float z = x * (1.5957691216057308f + 0.0713551f * x2);
  float e = __expf(z);
  float r = 1.0f - __frcp_rn(e + 1.0f);
  return x * r;
}
// bf16 conversions through HIP intrinsics so the compiler can emit
// v_cvt_pk_bf16_f32 (RNE — bit-identical to the old manual path).
DEV ushort f2bf(float x) {
  __hip_bfloat16 b = __float2bfloat16(x);
  union { __hip_bfloat16 h; ushort u; } cv;
  cv.h = b;
  return cv.u;
}
DEV unsigned f2bf2(float lo, float hi) {
  __hip_bfloat162 b2 = __float22bfloat162_rn(make_float2(lo, hi));
  union { __hip_bfloat162 h; unsigned u; } cv;
  cv.h = b2;
  return cv.u;
}
// bf16 rotated row store (width 128): element (row,col)
DEV void stb128(ushort* b, int row, int col, float v) {
  b[row * 128 + (((col & ~7) + 8 * row) & 127) + (col & 7)] = f2bf(v);
}

// ============ 0a. weight prep: fp32 [K][N] -> bf16 [N][K], 4 levels ========
__global__ __launch_bounds__(256) void wprep_all_kernel(
    const float* __restrict__ src0, ushort* __restrict__ dst0, int K, int N) {
  size_t off = (size_t)blockIdx.z * K * N;
  const float* src = src0 + off;
  ushort* dst = dst0 + off;
  __shared__ float S[64][65];
  int tid = threadIdx.x;
  int k0 = blockIdx.x * 64, n0 = blockIdx.y * 64;
  for (int i = tid; i < 64 * 64; i += 256) {
    int kk = i >> 6, nn = i & 63;
    S[kk][nn] = src[(size_t)(k0 + kk) * N + n0 + nn];
  }
  __syncthreads();
  int n = tid >> 2, kq = tid & 3;
  unsigned pk[8];
#pragma unroll
  for (int i = 0; i < 8; i++) {
    int k = kq * 16 + 2 * i;
    pk[i] = f2bf2(S[k][n], S[k + 1][n]);
  }
  unsigned* dp = (unsigned*)&dst[(size_t)(n0 + n) * K + k0 + kq * 16];
#pragma unroll
  for (int i = 0; i < 8; i++) dp[i] = pk[i];
}

// ====== 0b. uv weight prep (all 8 matrices in one launch) ==================
struct UVDesc {
  const float* src[8];
  ushort* dst[8];
  int expj[8];
  int npad[8];
};
__global__ __launch_bounds__(256) void uvprep_all_kernel(UVDesc d) {
  int mi = blockIdx.y;
  int i = blockIdx.x * 256 + threadIdx.x;
  int expj = d.expj[mi];
  if (i >= d.npad[mi] * 128) return;
  int n = i >> 7, k = i & 127;
  d.dst[mi][(size_t)n * 128 + k] =
      (n < expj) ? f2bf(d.src[mi][(size_t)k * expj + n]) : (ushort)0;
}

// ====== 0c. effective node-embed weights + RoPE table ======================
__global__ __launch_bounds__(128) void weff_prep_kernel(
    const float* __restrict__ cw, const float* __restrict__ cb,
    const float* __restrict__ nw, const float* __restrict__ nb,
    const float* __restrict__ iw, const float* __restrict__ ib,
    float* __restrict__ weff, float* __restrict__ ropetab) {
  __shared__ float S[11 * 128];
  int tid = threadIdx.x;
  for (int i = tid; i < 512; i += 128) S[i] = cw[i];
  for (int i = tid; i < 640; i += 128) S[512 + i] = nw[i];
  S[1152 + tid] = nb[tid];
  S[1280 + tid] = cb[tid];
  __syncthreads();
  float acc[11];
#pragma unroll
  for (int r = 0; r < 10; r++) acc[r] = 0.f;
  acc[10] = ib[tid];
  for (int k = 0; k < 128; k++) {
    float w = iw[k * 128 + tid];
#pragma unroll
    for (int r = 0; r < 11; r++) acc[r] += S[r * 128 + k] * w;
  }
#pragma unroll
  for (int r = 0; r < 11; r++) weff[r * 128 + tid] = acc[r];
  for (int idx = tid; idx < 512; idx += 128) {
    int pos = idx >> 4, d = idx & 15;
    float ang = (float)pos * expf(-0.57564627324851148f * (float)d);
    ropetab[idx] = cosf(ang);
    ropetab[512 + idx] = sinf(ang);
  }
}

// ============ 1. node embedding (collapsed linear form) ====================
__global__ __launch_bounds__(256) void node_embed2_kernel(
    const float* __restrict__ x, const float* __restrict__ weff,
    float* __restrict__ h) {
  __shared__ float XR[64 * XFv];
  __shared__ float RF[64][11];
  __shared__ __align__(16) float WE[11 * 128];
  int tid = threadIdx.x;
  int node0 = blockIdx.x * 64;
  for (int i = tid; i < 64 * XFv; i += 256)
    XR[i] = x[(size_t)node0 * XFv + i];
  for (int i = tid; i < 11 * 128; i += 256) WE[i] = weff[i];
  __syncthreads();
  {
    int nn = tid >> 2, sl = tid & 3;
    const float* xr = XR + nn * XFv;
    float p0 = xr[0], p1 = xr[1], p2 = xr[2];
    float g[6] = {0.f, 0.f, 0.f, 0.f, 0.f, 0.f};
#pragma unroll
    for (int s = 0; s < 6; s++) {
      const float* f = xr + 4 + 5 * (sl * 6 + s);
      float w = f[4];
      if (w != 0.0f) {
        g[0] += f[0]; g[1] += f[1] - p0; g[2] += f[2] - p1;
        g[3] += f[3] - p2; g[4] += w; g[5] += 1.0f;
      }
    }
#pragma unroll
    for (int i = 0; i < 6; i++) {
      g[i] += __shfl_xor(g[i], 1);
      g[i] += __shfl_xor(g[i], 2);
    }
    if (sl == 0) {
      RF[nn][0] = p0; RF[nn][1] = p1; RF[nn][2] = p2; RF[nn][3] = xr[3];
#pragma unroll
      for (int i = 0; i < 6; i++) RF[nn][4 + i] = g[i];
    }
  }
  __syncthreads();
  {
    int w = tid >> 6, lane = tid & 63;
    int c4 = lane & 31, hi = lane >> 5;
    const float4* WE4 = (const float4*)WE;
#pragma unroll
    for (int rr = 0; rr < 8; rr++) {
      int node = w * 16 + rr * 2 + hi;
      float4 acc = WE4[10 * 32 + c4];
#pragma unroll
      for (int f = 0; f < 10; f++)
        fma4(acc, RF[node][f], WE4[f * 32 + c4]);
      *(float4*)&h[(size_t)(node0 + node) * 128 + c4 * 4] = acc;
    }
  }
}

// ============================ 2. leaf dense ================================
__global__ __launch_bounds__(256) void leaf_dense_kernel(
    const float* __restrict__ h, const float* __restrict__ x,
    const float* __restrict__ lpw, const float* __restrict__ lpb,
    const float* __restrict__ lhw, const float* __restrict__ lhb,
    const float* __restrict__ lsc, float* __restrict__ out) {
  __shared__ __align__(16) float HS[32 * 128];
  __shared__ __align__(16) float HL[32 * 32];
  __shared__ __align__(16) float UL[32 * 32];
  int tid = threadIdx.x;
  int leaf = blockIdx.x;
  size_t base = (size_t)leaf * (32 * 128);
  for (int i = tid; i < 32 * 128; i += 256) {
    int t = i >> 7, c = i & 127;
    at1r(HS, t, c, 128) = h[base + i];
  }
  __syncthreads();
  int t = tid & 31, cg = tid >> 5;
  {
    float4 acc = ld4g(&lpb[4 * cg]);
    for (int k4 = 0; k4 < 128; k4 += 4) {
      float4 xv = *(const float4*)at4p(HS, t, k4, 128);
      float xa[4] = {xv.x, xv.y, xv.z, xv.w};
#pragma unroll
      for (int kk = 0; kk < 4; kk++)
        fma4(acc, xa[kk], ld4g(&lpw[(k4 + kk) * 32 + 4 * cg]));
    }
    *(float4*)at4p(HL, t, 4 * cg, 32) = acc;
  }
  __syncthreads();
  {
    float4 acc = ld4g(&lhb[4 * cg]);
    for (int k4 = 0; k4 < 32; k4 += 4) {
      float4 xv = *(const float4*)at4p(HL, t, k4, 32);
      float xa[4] = {xv.x, xv.y, xv.z, xv.w};
#pragma unroll
      for (int kk = 0; kk < 4; kk++)
        fma4(acc, xa[kk], ld4g(&lhw[(k4 + kk) * 32 + 4 * cg]));
    }
    *(float4*)at4p(UL, t, 4 * cg, 32) = acc;
  }
  __syncthreads();
  {
    float scale = expf(lsc[0]);
    float acc[4] = {0.f, 0.f, 0.f, 0.f};
    for (int k4 = 0; k4 < 32; k4 += 4) {
      float4 xv = *(const float4*)at4p(UL, t, k4, 32);
      float xa[4] = {xv.x, xv.y, xv.z, xv.w};
#pragma unroll
      for (int kk = 0; kk < 4; kk++) {
        int k = k4 + kk;
#pragma unroll
        for (int i2 = 0; i2 < 4; i2++)
          acc[i2] += xa[kk] * at1r(UL, 4 * cg + i2, k, 32);
      }
    }
    int b = leaf >> 8, l = leaf & 255;
#pragma unroll
    for (int i2 = 0; i2 < 4; i2++) {
      int c = 4 * cg + i2;
      float v = acc[i2] * scale;
      if (c == t) {
        float dg = x[(size_t)(leaf * 32 + t) * XFv + 3];
        v += (fabsf(dg) > 1e-6f) ? (1.0f / dg) : 1.0f;
      }
      out[(size_t)b * OPB + (size_t)l * 1024 + t * 32 + c] = v;
    }
  }
}

// ========== 3. fused transformer layer: attn + mlp (32-token tiles) ========
// Round-9 proven structure (best counters; total ~422us). cvt_pk bf16
// conversions, 256-thread softmax, double-buffered mlp (1 barrier/chunk).
__global__ __launch_bounds__(256, 4) void layer_mfma_kernel(
    float* __restrict__ h,
    const float* __restrict__ lng, const float* __restrict__ lnb,
    const ushort* __restrict__ wqkvt, const float* __restrict__ bqkv,
    const ushort* __restrict__ wpt, const float* __restrict__ pb,
    const float* __restrict__ rt,
    const float* __restrict__ ln2g, const float* __restrict__ ln2b,
    const ushort* __restrict__ w1t, const float* __restrict__ b1,
    const ushort* __restrict__ w2t, const float* __restrict__ b2) {
  __shared__ __align__(16) ushort SM[20480];   // 40 KB
  ushort* XN = SM;            // R0 [0,8KB)
  ushort* QB = SM + 4096;     // R1 [8,16KB)
  ushort* KB = SM + 8192;     // R2 [16,24KB)
  ushort* VT = SM + 12288;    // R3 [24,32KB)
  ushort* HC1 = SM + 16384;   // R4 [32,40KB) (mlp hidden buf 1)
  float*  HS = (float*)(SM + 8192);   // fp32 32x128 over R2+R3
  int tid = threadIdx.x;
  size_t base = (size_t)blockIdx.x * (32 * 128);
  int w = tid >> 6, l = tid & 63, lm = l & 15, q = l >> 4;

  { // --- A: LayerNorm1 -> bf16 XN (8 threads/token, 16 cols each) ---
    int m8 = tid >> 3, p8 = tid & 7;
    const float* row = h + base + m8 * 128 + p8 * 16;
    float v[16];
    float s = 0.f;
#pragma unroll
    for (int i = 0; i < 16; i += 4) {
      float4 t4 = ld4g(row + i);
      v[i] = t4.x; v[i + 1] = t4.y; v[i + 2] = t4.z; v[i + 3] = t4.w;
      s += t4.x + t4.y + t4.z + t4.w;
    }
    s += __shfl_xor(s, 1); s += __shfl_xor(s, 2); s += __shfl_xor(s, 4);
    float mu = s * (1.0f / 128.0f);
    float s2 = 0.f;
#pragma unroll
    for (int i = 0; i < 16; i++) { float d = v[i] - mu; s2 += d * d; }
    s2 += __shfl_xor(s2, 1); s2 += __shfl_xor(s2, 2); s2 += __shfl_xor(s2, 4);
    float rs = rsqrtf(s2 * (1.0f / 128.0f) + 1e-5f);
    unsigned* XW = (unsigned*)XN;
#pragma unroll
    for (int i = 0; i < 16; i += 2) {
      int c = p8 * 16 + i;
      float x0 = (v[i] - mu) * rs * lng[c] + lnb[c];
      float x1 = (v[i + 1] - mu) * rs * lng[c + 1] + lnb[c + 1];
      int kp = c >> 1;
      XW[m8 * 64 + ((kp + 4 * m8) & 63)] = f2bf2(x0, x1);
    }
  }
  __syncthreads();

  { // --- B: qkv GEMM (M=32) + RoPE via table ---
    f32x4v acc[2][6];
#pragma unroll
    for (int mt = 0; mt < 2; mt++)
#pragma unroll
      for (int nt = 0; nt < 6; nt++) acc[mt][nt] = (f32x4v){0.f, 0.f, 0.f, 0.f};
    for (int ks = 0; ks < 4; ks++) {
      bfrag a[2];
#pragma unroll
      for (int mt = 0; mt < 2; mt++) {
        int mm = mt * 16 + lm;
        a[mt] = *(const bfrag*)&XN[mm * 128 + ((ks * 32 + q * 8 + 8 * mm) & 127)];
      }
#pragma unroll
      for (int nt = 0; nt < 6; nt++) {
        int n = w * 96 + nt * 16 + lm;
        bfrag b = *(const bfrag*)&wqkvt[(size_t)n * 128 + ks * 32 + q * 8];
#pragma unroll
        for (int mt = 0; mt < 2; mt++)
          acc[mt][nt] = __builtin_amdgcn_mfma_f32_16x16x32_bf16(
              a[mt], b, acc[mt][nt], 0, 0, 0);
      }
    }
    float csA[4] = {}, snA[4] = {}, csB[4] = {}, snB[4] = {};
    if (w < 3) {   // only q/k waves rotate
#pragma unroll
      for (int r = 0; r < 4; r++) {
        int pa = q * 4 + r;
        csA[r] = rt[pa * 16 + lm];        snA[r] = rt[512 + pa * 16 + lm];
        csB[r] = rt[(pa + 16) * 16 + lm]; snB[r] = rt[512 + (pa + 16) * 16 + lm];
      }
    }
#pragma unroll
    for (int p2 = 0; p2 < 3; p2++) {
      int g = w * 6 + 2 * p2;
      int ne = g * 16 + lm;
      if (g < 16) {
        float be = bqkv[ne], bo = bqkv[ne + 16];
        ushort* dst = (g < 8) ? QB : KB;
        int de = (g < 8) ? ne : ne - 128;
#pragma unroll
        for (int mt = 0; mt < 2; mt++)
#pragma unroll
          for (int r = 0; r < 4; r++) {
            int mm = mt * 16 + q * 4 + r;
            float cs = (mt & 1) ? csB[r] : csA[r];
            float sn = (mt & 1) ? snB[r] : snA[r];
            float e = acc[mt][2 * p2][r] + be;
            float o = acc[mt][2 * p2 + 1][r] + bo;
            stb128(dst, mm, de, e * cs - o * sn);
            stb128(dst, mm, de + 16, o * cs + e * sn);
          }
      } else {
#pragma unroll
        for (int h2 = 0; h2 < 2; h2++) {
          int nt = 2 * p2 + h2;
          int nv = (g + h2) * 16 + lm;
          int dv = nv - 256;
          float bv = bqkv[nv];
#pragma unroll
          for (int mt = 0; mt < 2; mt++) {
            int t0 = mt * 16 + q * 4;
            uint2 pk;
            pk.x = f2bf2(acc[mt][nt][0] + bv, acc[mt][nt][1] + bv);
            pk.y = f2bf2(acc[mt][nt][2] + bv, acc[mt][nt][3] + bv);
            *(uint2*)&VT[dv * 32 + (((t0 & ~7) + 8 * dv) & 31) + (t0 & 7)] = pk;
          }
        }
      }
    }
  }
  __syncthreads();

  ushort* SP = XN;   // scores overlay XN (dead after B)
  { // --- C: scores (wave = head) ---
    int head = w;
    f32x4v sc[2][2];
#pragma unroll
    for (int a2 = 0; a2 < 2; a2++)
#pragma unroll
      for (int b2 = 0; b2 < 2; b2++) sc[a2][b2] = (f32x4v){0.f, 0.f, 0.f, 0.f};
    bfrag qa[2], kb[2];
#pragma unroll
    for (int mt2 = 0; mt2 < 2; mt2++) {
      int row = mt2 * 16 + lm;
      qa[mt2] = *(const bfrag*)&QB[row * 128 + ((head * 32 + q * 8 + 8 * row) & 127)];
    }
#pragma unroll
    for (int nt2 = 0; nt2 < 2; nt2++) {
      int kt = nt2 * 16 + lm;
      kb[nt2] = *(const bfrag*)&KB[kt * 128 + ((head * 32 + q * 8 + 8 * kt) & 127)];
    }
#pragma unroll
    for (int mt2 = 0; mt2 < 2; mt2++)
#pragma unroll
      for (int nt2 = 0; nt2 < 2; nt2++)
        sc[mt2][nt2] = __builtin_amdgcn_mfma_f32_16x16x32_bf16(
            qa[mt2], kb[nt2], sc[mt2][nt2], 0, 0, 0);
    const float scl = 0.17677669529663688f;
#pragma unroll
    for (int mt2 = 0; mt2 < 2; mt2++)
#pragma unroll
      for (int nt2 = 0; nt2 < 2; nt2++)
#pragma unroll
        for (int r = 0; r < 4; r++) {
          int qt = mt2 * 16 + q * 4 + r;
          int kc = nt2 * 16 + lm;
          SP[head * 1024 + qt * 32 + (((kc & ~7) + 8 * qt) & 31) + (kc & 7)] =
              f2bf(sc[mt2][nt2][r] * scl);
        }
  }
  __syncthreads();

  { // --- D: softmax (all 256 threads: 2 threads per row) ---
    int rowid = tid >> 1, half = tid & 1;
    int head = rowid >> 5, qt = rowid & 31;
    ushort* rowp = SP + head * 1024 + qt * 32 + half * 16;
    float v[16];
#pragma unroll
    for (int pc = 0; pc < 2; pc++) {
      uint4 ch = *(const uint4*)&rowp[pc * 8];
      unsigned uu[4] = {ch.x, ch.y, ch.z, ch.w};
#pragma unroll
      for (int i2 = 0; i2 < 4; i2++) {
        v[pc * 8 + 2 * i2]     = __uint_as_float(uu[i2] << 16);
        v[pc * 8 + 2 * i2 + 1] = __uint_as_float(uu[i2] & 0xffff0000u);
      }
    }
    float mx = -1e30f;
#pragma unroll
    for (int i = 0; i < 16; i++) mx = fmaxf(mx, v[i]);
    mx = fmaxf(mx, __shfl_xor(mx, 1));
    float s = 0.f;
#pragma unroll
    for (int i = 0; i < 16; i++) { v[i] = __expf(v[i] - mx); s += v[i]; }
    s += __shfl_xor(s, 1);
    float inv = 1.0f / s;
#pragma unroll
    for (int pc = 0; pc < 2; pc++) {
      uint4 ch;
      unsigned uu[4];
#pragma unroll
      for (int i2 = 0; i2 < 4; i2++)
        uu[i2] = f2bf2(v[pc * 8 + 2 * i2] * inv, v[pc * 8 + 2 * i2 + 1] * inv);
      ch.x = uu[0]; ch.y = uu[1]; ch.z = uu[2]; ch.w = uu[3];
      *(uint4*)&rowp[pc * 8] = ch;
    }
  }
  __syncthreads();

  ushort* OB = QB;   // attn-out overlays QB (dead after C)
  { // --- E: O = P @ V (wave = head) ---
    int head = w;
    f32x4v ov[2][2];
#pragma unroll
    for (int a2 = 0; a2 < 2; a2++)
#pragma unroll
      for (int b2 = 0; b2 < 2; b2++) ov[a2][b2] = (f32x4v){0.f, 0.f, 0.f, 0.f};
    bfrag pa[2], vb2[2];
#pragma unroll
    for (int mt2 = 0; mt2 < 2; mt2++) {
      int qt = mt2 * 16 + lm;
      pa[mt2] = *(const bfrag*)&SP[head * 1024 + qt * 32 + ((q * 8 + 8 * qt) & 31)];
    }
#pragma unroll
    for (int nt2 = 0; nt2 < 2; nt2++) {
      int gdim = head * 32 + nt2 * 16 + lm;
      vb2[nt2] = *(const bfrag*)&VT[gdim * 32 + ((q * 8 + 8 * gdim) & 31)];
    }
#pragma unroll
    for (int mt2 = 0; mt2 < 2; mt2++)
#pragma unroll
      for (int nt2 = 0; nt2 < 2; nt2++)
        ov[mt2][nt2] = __builtin_amdgcn_mfma_f32_16x16x32_bf16(
            pa[mt2], vb2[nt2], ov[mt2][nt2], 0, 0, 0);
#pragma unroll
    for (int mt2 = 0; mt2 < 2; mt2++)
#pragma unroll
      for (int nt2 = 0; nt2 < 2; nt2++)
#pragma unroll
        for (int r = 0; r < 4; r++) {
          int qt = mt2 * 16 + q * 4 + r;
          int gdim = head * 32 + nt2 * 16 + lm;
          stb128(OB, qt, gdim, ov[mt2][nt2][r]);
        }
  }
  __syncthreads();

  { // --- F: out-proj -> HS = attn_out + pb (fp32, 4-rotated rows) ---
    f32x4v po[2][2];
#pragma unroll
    for (int mt = 0; mt < 2; mt++)
#pragma unroll
      for (int nt = 0; nt < 2; nt++) po[mt][nt] = (f32x4v){0.f, 0.f, 0.f, 0.f};
    for (int ks = 0; ks < 4; ks++) {
      bfrag a[2];
#pragma unroll
      for (int mt = 0; mt < 2; mt++) {
        int mm = mt * 16 + lm;
        a[mt] = *(const bfrag*)&OB[mm * 128 + ((ks * 32 + q * 8 + 8 * mm) & 127)];
      }
#pragma unroll
      for (int nt = 0; nt < 2; nt++) {
        int n = w * 32 + nt * 16 + lm;
        bfrag b = *(const bfrag*)&wpt[(size_t)n * 128 + ks * 32 + q * 8];
#pragma unroll
        for (int mt = 0; mt < 2; mt++)
          po[mt][nt] = __builtin_amdgcn_mfma_f32_16x16x32_bf16(
              a[mt], b, po[mt][nt], 0, 0, 0);
      }
    }
#pragma unroll
    for (int nt = 0; nt < 2; nt++) {
      int n = w * 32 + nt * 16 + lm;
      float bv = pb[n];
#pragma unroll
      for (int mt = 0; mt < 2; mt++)
#pragma unroll
        for (int r = 0; r < 4; r++) {
          int mm = mt * 16 + q * 4 + r;
          at1r(HS, mm, n, 128) = po[mt][nt][r] + bv;
        }
    }
  }
  __syncthreads();

  { // --- G: hn = h + attn_out (in HS); LayerNorm2 -> bf16 XN2 ---
    int j = tid & 31;
    int c0 = j * 4;
    float g0 = ln2g[c0], g1 = ln2g[c0 + 1], g2 = ln2g[c0 + 2], g3 = ln2g[c0 + 3];
    float e0 = ln2b[c0], e1 = ln2b[c0 + 1], e2 = ln2b[c0 + 2], e3 = ln2b[c0 + 3];
    unsigned* XW = (unsigned*)XN;
#pragma unroll
    for (int k2 = 0; k2 < 4; k2++) {
      int idx = tid + 256 * k2;
      int tok = idx >> 5;
      float4 hg = ld4g(&h[base + (size_t)idx * 4]);
      float4 ao = *(const float4*)at4p(HS, tok, 4 * j, 128);
      float4 hn;
      hn.x = hg.x + ao.x; hn.y = hg.y + ao.y;
      hn.z = hg.z + ao.z; hn.w = hg.w + ao.w;
      *(float4*)at4p(HS, tok, 4 * j, 128) = hn;
      float s = hn.x + hn.y + hn.z + hn.w;
      s += __shfl_xor(s, 1); s += __shfl_xor(s, 2); s += __shfl_xor(s, 4);
      s += __shfl_xor(s, 8); s += __shfl_xor(s, 16);
      float mu = s * (1.0f / 128.0f);
      float d0 = hn.x - mu, d1 = hn.y - mu, d2 = hn.z - mu, d3 = hn.w - mu;
      float s2 = d0 * d0 + d1 * d1 + d2 * d2 + d3 * d3;
      s2 += __shfl_xor(s2, 1); s2 += __shfl_xor(s2, 2); s2 += __shfl_xor(s2, 4);
      s2 += __shfl_xor(s2, 8); s2 += __shfl_xor(s2, 16);
      float rs = rsqrtf(s2 * (1.0f / 128.0f) + 1e-5f);
      float x0 = d0 * rs * g0 + e0;
      float x1 = d1 * rs * g1 + e1;
      float x2 = d2 * rs * g2 + e2;
      float x3 = d3 * rs * g3 + e3;
      int kp = 2 * j;
      XW[tok * 64 + ((kp + 4 * tok) & 63)] = f2bf2(x0, x1);
      XW[tok * 64 + ((kp + 1 + 4 * tok) & 63)] = f2bf2(x2, x3);
    }
  }
  __syncthreads();

  // --- mlp: 4 hidden chunks, double-buffered HC, 1 barrier/chunk ---
  ushort* HC0 = QB;
  f32x4v acc2[2][2];
#pragma unroll
  for (int mt = 0; mt < 2; mt++)
#pragma unroll
    for (int nt = 0; nt < 2; nt++) acc2[mt][nt] = (f32x4v){0.f, 0.f, 0.f, 0.f};

  auto mlp1_calc = [&](int hc, f32x4v A1[2][2]) {
#pragma unroll
    for (int mt = 0; mt < 2; mt++)
#pragma unroll
      for (int nt = 0; nt < 2; nt++) A1[mt][nt] = (f32x4v){0.f, 0.f, 0.f, 0.f};
#pragma unroll
    for (int ks = 0; ks < 4; ks++) {
      bfrag a[2];
#pragma unroll
      for (int mt = 0; mt < 2; mt++) {
        int mm = mt * 16 + lm;
        a[mt] = *(const bfrag*)&XN[mm * 128 + ((ks * 32 + q * 8 + 8 * mm) & 127)];
      }
#pragma unroll
      for (int nt = 0; nt < 2; nt++) {
        int n = hc * 128 + w * 32 + nt * 16 + lm;
        bfrag b = *(const bfrag*)&w1t[(size_t)n * 128 + ks * 32 + q * 8];
#pragma unroll
        for (int mt = 0; mt < 2; mt++)
          A1[mt][nt] = __builtin_amdgcn_mfma_f32_16x16x32_bf16(
              a[mt], b, A1[mt][nt], 0, 0, 0);
      }
    }
  };
  auto gelu_store = [&](int hc, f32x4v A1[2][2], ushort* HCd) {
#pragma unroll
    for (int nt = 0; nt < 2; nt++) {
      int nl = w * 32 + nt * 16 + lm;
      float b1v = b1[hc * 128 + nl];
#pragma unroll
      for (int mt = 0; mt < 2; mt++)
#pragma unroll
        for (int r = 0; r < 4; r++) {
          int mm = mt * 16 + q * 4 + r;
          float val = gelu_fast(A1[mt][nt][r] + b1v);
          HCd[mm * 128 + (((nl & ~7) + 8 * mm) & 127) + (nl & 7)] = f2bf(val);
        }
    }
  };
  auto mlp2_calc = [&](int hc, ushort* HCr) {
#pragma unroll
    for (int ks = 0; ks < 4; ks++) {
      bfrag a[2];
#pragma unroll
      for (int mt = 0; mt < 2; mt++) {
        int mm = mt * 16 + lm;
        a[mt] = *(const bfrag*)&HCr[mm * 128 + ((ks * 32 + q * 8 + 8 * mm) & 127)];
      }
#pragma unroll
      for (int nt = 0; nt < 2; nt++) {
        int n = w * 32 + nt * 16 + lm;
        bfrag b = *(const bfrag*)&w2t[(size_t)n * 512 + hc * 128 + ks * 32 + q * 8];
#pragma unroll
        for (int mt = 0; mt < 2; mt++)
          acc2[mt][nt] = __builtin_amdgcn_mfma_f32_16x16x32_bf16(
              a[mt], b, acc2[mt][nt], 0, 0, 0);
      }
    }
  };

  f32x4v a1A[2][2], a1B[2][2];
  mlp1_calc(0, a1A);
  gelu_store(0, a1A, HC0);
  __syncthreads();
  mlp1_calc(1, a1B);        // overlaps with other waves' mlp2(0)
  mlp2_calc(0, HC0);
  gelu_store(1, a1B, HC1);
  __syncthreads();
  mlp1_calc(2, a1A);
  mlp2_calc(1, HC1);
  gelu_store(2, a1A, HC0);
  __syncthreads();
  mlp1_calc(3, a1B);
  mlp2_calc(2, HC0);
  gelu_store(3, a1B, HC1);
  __syncthreads();
  mlp2_calc(3, HC1);

  // --- epilogue: h = hn (HS) + mlp_out + b2 — the ONLY global h write ---
#pragma unroll
  for (int nt = 0; nt < 2; nt++) {
    int n = w * 32 + nt * 16 + lm;
    float b2v = b2[n];
#pragma unroll
    for (int mt = 0; mt < 2; mt++)
#pragma unroll
      for (int r = 0; r < 4; r++) {
        int mm = mt * 16 + q * 4 + r;
        h[base + (size_t)mm * 128 + n] = at1r(HS, mm, n, 128) + acc2[mt][nt][r] + b2v;
      }
  }
}

// ====== 5. uv heads + downsample, fused (64-token tiles, compact stg) ======
template <int EXPJ, int RANK, int LVL, int NSPLIT>
__global__ __launch_bounds__(256) void uvds_kernel(
    const float* __restrict__ h,
    const ushort* __restrict__ uwt, const float* __restrict__ ub,
    const ushort* __restrict__ vwt, const float* __restrict__ vb,
    float* __restrict__ ustg, float* __restrict__ vstg,
    float* __restrict__ hout,
    const ushort* __restrict__ dwt, const float* __restrict__ dsb) {
  constexpr int NT16 = (EXPJ + 15) / 16;
  constexpr int NJOBS = 2 * NT16;
  __shared__ __align__(16) ushort XN[64 * 128];
  int tid = threadIdx.x;
  int t0 = blockIdx.x * 64;
  size_t base = (size_t)t0 * 128;
  {
    int m = tid >> 2, p = tid & 3;
    const float* row = h + base + m * 128 + p * 32;
    unsigned* XW = (unsigned*)XN;
#pragma unroll
    for (int i = 0; i < 32; i += 4) {
      float4 t4 = ld4g(row + i);
      int kp = (p * 32 + i) >> 1;
      XW[m * 64 + ((kp + 4 * m) & 63)] = f2bf2(t4.x, t4.y);
      XW[m * 64 + ((kp + 1 + 4 * m) & 63)] = f2bf2(t4.z, t4.w);
    }
  }
  __syncthreads();
  int w = tid >> 6, l = tid & 63, lm = l & 15, q = l >> 4;
  int gw = w + 4 * blockIdx.y;
  for (int jj = gw; jj < NJOBS; jj += 4 * NSPLIT) {
    int uvsel = jj & 1, nt = jj >> 1;
    const ushort* wt = uvsel ? vwt : uwt;
    const float* bias = uvsel ? vb : ub;
    float* stg = uvsel ? vstg : ustg;
    f32x4v acc[4];
#pragma unroll
    for (int mt = 0; mt < 4; mt++) acc[mt] = (f32x4v){0.f, 0.f, 0.f, 0.f};
    for (int ks = 0; ks < 4; ks++) {
      bfrag b = *(const bfrag*)&wt[(size_t)(nt * 16 + lm) * 128 + ks * 32 + q * 8];
#pragma unroll
      for (int mt = 0; mt < 4; mt++) {
        int mm = mt * 16 + lm;
        int ke = ks * 32 + q * 8;
        bfrag a = *(const bfrag*)&XN[mm * 128 + ((ke + 8 * mm) & 127)];
        acc[mt] = __builtin_amdgcn_mfma_f32_16x16x32_bf16(a, b, acc[mt], 0, 0, 0);
      }
    }
    int c = nt * 16 + lm;
    if (c < EXPJ) {
      float bv = bias[c];
#pragma unroll
      for (int mt = 0; mt < 4; mt++)
#pragma unroll
        for (int r = 0; r < 4; r++) {
          int mm = mt * 16 + q * 4 + r;
          stg[(size_t)(t0 + mm) * EXPJ + c] = acc[mt][r] + bv;
        }
    }
  }
  if constexpr (LVL < 3) {
    if (blockIdx.y == 0) { // --- downsample: 64 tokens -> 32 rows of 128 ---
      f32x4v dacc[2][2];
#pragma unroll
      for (int mt = 0; mt < 2; mt++)
#pragma unroll
        for (int nt = 0; nt < 2; nt++) dacc[mt][nt] = (f32x4v){0.f, 0.f, 0.f, 0.f};
      for (int ks = 0; ks < 8; ks++) {
        bfrag a[2];
#pragma unroll
        for (int mt = 0; mt < 2; mt++) {
          int rr = mt * 16 + lm;
          int tok = 2 * rr + (ks >> 2);
          int c2 = (ks & 3) * 32 + q * 8;
          a[mt] = *(const bfrag*)&XN[tok * 128 + ((c2 + 8 * tok) & 127)];
        }
#pragma unroll
        for (int nt = 0; nt < 2; nt++) {
          int n = w * 32 + nt * 16 + lm;
          bfrag b = *(const bfrag*)&dwt[(size_t)n * 256 + ks * 32 + q * 8];
#pragma unroll
          for (int mt = 0; mt < 2; mt++)
            dacc[mt][nt] = __builtin_amdgcn_mfma_f32_16x16x32_bf16(
                a[mt], b, dacc[mt][nt], 0, 0, 0);
        }
      }
      size_t ob2 = (size_t)blockIdx.x * (32 * 128);
#pragma unroll
      for (int nt = 0; nt < 2; nt++) {
        int n = w * 32 + nt * 16 + lm;
        float bv = dsb[n];
#pragma unroll
        for (int mt = 0; mt < 2; mt++)
#pragma unroll
          for (int r = 0; r < 4; r++) {
            int mm = mt * 16 + q * 4 + r;
            hout[ob2 + (size_t)mm * 128 + n] = dacc[mt][nt][r] + bv;
          }
      }
    }
  }
}

// ====== 6. final uv assembly: staging -> out rows, fully contiguous ========
struct StgPtrs { const float* u[4]; const float* v[4]; };
__global__ __launch_bounds__(256) void uv_assemble_kernel(
    StgPtrs sp, float* __restrict__ out) {
  __shared__ unsigned char JL[93];
  __shared__ unsigned char CM[93];
  int tid = threadIdx.x;
  if (tid < 93) {
    int c = 2 * tid;
    int j = (c < 20) ? 0 : (c < 52) ? 1 : (c < 104) ? 2 : 3;
    int coff = (j == 0) ? 0 : (j == 1) ? 20 : (j == 2) ? 52 : 104;
    JL[tid] = (unsigned char)j;
    CM[tid] = (unsigned char)(c - coff);
  }
  __syncthreads();
  int g0 = blockIdx.x * 32;   // 32 global node-rows per block
  for (int i = tid; i < 32 * 93; i += 256) {
    int rr = i / 93, cp = i - rr * 93;
    int g = g0 + rr;
    int b = g >> 13, n = g & 8191;
    int j = JL[cp], cm = CM[cp];
    int expj, rank;
    if (j == 0)      { expj = 20;  rank = 20; }
    else if (j == 1) { expj = 64;  rank = 32; }
    else if (j == 2) { expj = 208; rank = 52; }
    else             { expj = 656; rank = 82; }
    int tok = (b << (13 - j)) + (n >> j);
    int cdiv = n & ((1 << j) - 1);
    size_t si = (size_t)tok * expj + cdiv * rank + cm;
    size_t ob = (size_t)b * OPB + (size_t)n * UVWID + 2 * cp;
    *(float2*)&out[ob + UBASE] = *(const float2*)&sp.u[j][si];
    *(float2*)&out[ob + VBASE] = *(const float2*)&sp.v[j][si];
  }
}

// ================================ host =====================================
extern "C" void kernel_launch(void* const* d_in, const int* in_sizes, int n_in,
                              void* d_out, int out_size, void* d_ws, size_t ws_size,
                              hipStream_t stream) {
  const float* x       = (const float*)d_in[0];
  const float* cen_w   = (const float*)d_in[1];
  const float* cen_b   = (const float*)d_in[2];
  const float* nbr_w   = (const float*)d_in[3];
  const float* nbr_b   = (const float*)d_in[4];
  const float* inp_w   = (const float*)d_in[5];
  const float* inp_b   = (const float*)d_in[6];
  const float* leafp_w = (const float*)d_in[7];
  const float* leafp_b = (const float*)d_in[8];
  const float* leafh_w = (const float*)d_in[9];
  const float* leafh_b = (const float*)d_in[10];
  const float* lscale  = (const float*)d_in[11];
  const float* ln1_g   = (const float*)d_in[12];
  const float* ln1_b   = (const float*)d_in[13];
  const float* qkv_w   = (const float*)d_in[14];
  const float* qkv_b   = (const float*)d_in[15];
  const float* attnp_w = (const float*)d_in[16];
  const float* attnp_b = (const float*)d_in[17];
  const float* ln2_g   = (const float*)d_in[18];
  const float* ln2_b   = (const float*)d_in[19];
  const float* mlp1_w  = (const float*)d_in[20];
  const float* mlp1_b  = (const float*)d_in[21];
  const float* mlp2_w  = (const float*)d_in[22];
  const float* mlp2_b  = (const float*)d_in[23];
  const float* ds_w    = (const float*)d_in[24];
  const float* ds_b    = (const float*)d_in[25];
  const float* huw[4], *hub[4], *hvw[4], *hvb[4];
  for (int j = 0; j < 4; j++) {
    huw[j] = (const float*)d_in[26 + 4 * j];
    hub[j] = (const float*)d_in[27 + 4 * j];
    hvw[j] = (const float*)d_in[28 + 4 * j];
    hvb[j] = (const float*)d_in[29 + 4 * j];
  }
  float* out = (float*)d_out;
  float* hA = (float*)d_ws;                       // 4*8192*128 fp32 = 16 MB
  float* hB = hA + (size_t)4 * 8192 * 128;        // 8 MB (ping-pong)
  ushort* w1t = (ushort*)(hB + (size_t)2097152);
  ushort* w2t = w1t + (size_t)4 * 65536;
  ushort* uvt = w2t + (size_t)4 * 65536;
  const int NPAD[4] = {32, 64, 208, 656};
  ushort* uwt[4]; ushort* vwt[4];
  ushort* p = uvt;
  for (int j = 0; j < 4; j++) {
    uwt[j] = p; p += (size_t)NPAD[j] * 128;
    vwt[j] = p; p += (size_t)NPAD[j] * 128;
  }
  ushort* wqkvt = p;                              // 4 levels x 384x128 bf16
  ushort* wpt   = wqkvt + (size_t)4 * 384 * 128;  // 4 levels x 128x128 bf16
  ushort* dswt  = wpt + (size_t)4 * 128 * 128;    // 4 levels x 128x256 bf16
  float* weff   = (float*)(dswt + (size_t)4 * 128 * 256);   // 11 x 128 fp32
  float* ropetab = weff + 1408;                   // 1024 floats
  // uv staging: [global_token][EXPJ] fp32 per level (u and v)
  const size_t STG[4] = {32768ull * 20, 16384ull * 64, 8192ull * 208, 4096ull * 656};
  float* ustg[4]; float* vstg[4];
  float* sp2 = ropetab + 1024;
  for (int j = 0; j < 4; j++) {
    ustg[j] = sp2; sp2 += STG[j];
    vstg[j] = sp2; sp2 += STG[j];
  }
  const int EXPJ_[4] = {20, 64, 208, 656};

  // stage 0: weight prep
  weff_prep_kernel<<<1, 128, 0, stream>>>(
      cen_w, cen_b, nbr_w, nbr_b, inp_w, inp_b, weff, ropetab);
  wprep_all_kernel<<<dim3(2, 8, 4), 256, 0, stream>>>(mlp1_w, w1t, 128, 512);
  wprep_all_kernel<<<dim3(8, 2, 4), 256, 0, stream>>>(mlp2_w, w2t, 512, 128);
  wprep_all_kernel<<<dim3(2, 6, 4), 256, 0, stream>>>(qkv_w, wqkvt, 128, 384);
  wprep_all_kernel<<<dim3(2, 2, 4), 256, 0, stream>>>(attnp_w, wpt, 128, 128);
  wprep_all_kernel<<<dim3(4, 2, 4), 256, 0, stream>>>(ds_w, dswt, 256, 128);
  {
    UVDesc d;
    for (int j = 0; j < 4; j++) {
      d.src[2 * j] = huw[j];     d.dst[2 * j] = uwt[j];
      d.src[2 * j + 1] = hvw[j]; d.dst[2 * j + 1] = vwt[j];
      d.expj[2 * j] = EXPJ_[j];  d.expj[2 * j + 1] = EXPJ_[j];
      d.npad[2 * j] = NPAD[j];   d.npad[2 * j + 1] = NPAD[j];
    }
    uvprep_all_kernel<<<dim3(328, 8), 256, 0, stream>>>(d);
  }

  // stage 1: node embedding -> hA
  node_embed2_kernel<<<(4 * 8192) / 64, 256, 0, stream>>>(x, weff, hA);
  // stage 2: leaf dense Gram
  leaf_dense_kernel<<<(4 * 8192) / 32, 256, 0, stream>>>(
      hA, x, leafp_w, leafp_b, leafh_w, leafh_b, lscale, out);

  // stage 3: 4 levels: fused attn+mlp layer, then fused uv+ds
  layer_mfma_kernel<<<32768 / 32, 256, 0, stream>>>(
      hA, ln1_g, ln1_b, wqkvt, qkv_b, wpt, attnp_b, ropetab,
      ln2_g, ln2_b, w1t, mlp1_b, w2t, mlp2_b);
  uvds_kernel<20, 20, 0, 1><<<dim3(512, 1), 256, 0, stream>>>(
      hA, uwt[0], hub[0], vwt[0], hvb[0], ustg[0], vstg[0],
      hB, dswt, ds_b);

  layer_mfma_kernel<<<16384 / 32, 256, 0, stream>>>(
      hB, ln1_g + 128, ln1_b + 128, wqkvt + 49152, qkv_b + 384,
      wpt + 16384, attnp_b + 128, ropetab,
      ln2_g + 128, ln2_b + 128, w1t + 65536, mlp1_b + 512,
      w2t + 65536, mlp2_b + 128);
  uvds_kernel<64, 32, 1, 2><<<dim3(256, 2), 256, 0, stream>>>(
      hB, uwt[1], hub[1], vwt[1], hvb[1], ustg[1], vstg[1],
      hA, dswt + 32768, ds_b + 128);

  layer_mfma_kernel<<<8192 / 32, 256, 0, stream>>>(
      hA, ln1_g + 256, ln1_b + 256, wqkvt + 98304, qkv_b + 768,
      wpt + 32768, attnp_b + 256, ropetab,
      ln2_g + 256, ln2_b + 256, w1t + 131072, mlp1_b + 1024,
      w2t + 131072, mlp2_b + 256);
  uvds_kernel<208, 52, 2, 4><<<dim3(128, 4), 256, 0, stream>>>(
      hA, uwt[2], hub[2], vwt[2], hvb[2], ustg[2], vstg[2],
      hB, dswt + 65536, ds_b + 256);

  layer_mfma_kernel<<<4096 / 32, 256, 0, stream>>>(
      hB, ln1_g + 384, ln1_b + 384, wqkvt + 147456, qkv_b + 1152,
      wpt + 49152, attnp_b + 384, ropetab,
      ln2_g + 384, ln2_b + 384, w1t + 196608, mlp1_b + 1536,
      w2t + 196608, mlp2_b + 384);
  uvds_kernel<656, 82, 3, 8><<<dim3(64, 8), 256, 0, stream>>>(
      hB, uwt[3], hub[3], vwt[3], hvb[3], ustg[3], vstg[3],
      hA /*unused*/, dswt /*unused*/, ds_b /*unused*/);

  // final: assemble uv rows contiguously
  {
    StgPtrs sp;
    for (int j = 0; j < 4; j++) { sp.u[j] = ustg[j]; sp.v[j] = vstg[j]; }
    uv_assemble_kernel<<<32768 / 32, 256, 0, stream>>>(sp, out);
  }
  (void)in_sizes; (void)n_in; (void)out_size; (void)ws_size;
}

// Round 13
// 398.638 us; speedup vs baseline: 1.4764x; 1.0463x over previous
//
#include <hip/hip_runtime.h>
#include <hip/hip_bf16.h>
#include <math.h>

#define DEV __device__ __forceinline__

constexpr int XFv = 124;              // features per node row
constexpr size_t OPB   = 3309568;     // output floats per batch
constexpr size_t UBASE = 262144;      // dense floats per batch
constexpr size_t VBASE = 1785856;     // UBASE + 8192*186
constexpr int UVWID = 186;            // 20+32+52+82

using bfrag  = __attribute__((ext_vector_type(8))) short;   // 8 bf16
using f32x4v = __attribute__((ext_vector_type(4))) float;   // MFMA acc

// --- rotated LDS layout helpers (fp32 tiles) ---
DEV float* at4p(float* base, int t, int c0, int W) {
  return base + t * W + ((c0 + 4 * t) & (W - 1));
}
DEV float& at1r(float* base, int t, int c, int W) {
  return base[t * W + (((c & ~3) + 4 * t) & (W - 1)) + (c & 3)];
}
DEV float4 ld4g(const float* p) { return *(const float4*)p; }
DEV void fma4(float4& a, float s, const float4& w) {
  a.x += s * w.x; a.y += s * w.y; a.z += s * w.z; a.w += s * w.w;
}
// tanh-form GELU: gelu(x) ~= x * e/(e+1), e = exp(x*(c1 + c2*x^2)).
DEV float gelu_fast(float x) {
  float x2 = x * x;
  float z = x * (1.5957691216057308f + 0.0713551f * x2);
  float e = __expf(z);
  float r = 1.0f - __frcp_rn(e + 1.0f);
  return x * r;
}
// bf16 conversions through HIP intrinsics so the compiler can emit
// v_cvt_pk_bf16_f32 (RNE — bit-identical to the old manual path).
DEV ushort f2bf(float x) {
  __hip_bfloat16 b = __float2bfloat16(x);
  union { __hip_bfloat16 h; ushort u; } cv;
  cv.h = b;
  return cv.u;
}
DEV unsigned f2bf2(float lo, float hi) {
  __hip_bfloat162 b2 = __float22bfloat162_rn(make_float2(lo, hi));
  union { __hip_bfloat162 h; unsigned u; } cv;
  cv.h = b2;
  return cv.u;
}
// bf16 rotated row store (width 128): element (row,col)
DEV void stb128(ushort* b, int row, int col, float v) {
  b[row * 128 + (((col & ~7) + 8 * row) & 127) + (col & 7)] = f2bf(v);
}

// ====== 0. ALL weight prep in ONE launch ===================================
// block 0:            weff (11x128 effective embed weights) + RoPE table
// blocks [1, 225):    5 transpose-prep jobs fp32[K][N]->bf16[N][K] x4 levels
// blocks [225, 2849): 8 uv weight matrices (pad + transpose to [N][128])
struct PrepArgs {
  const float *cw, *cb, *nw, *nb, *iw, *ib;
  float *weff, *ropetab;
  const float* wsrc[5]; ushort* wdst[5];
  int K[5], N[5], bx[5], by[5], base[5];
  const float* usrc[8]; ushort* udst[8];
  int expj[8], npad8[8];
  int ubase;
};
__global__ __launch_bounds__(256) void prep_all_kernel(PrepArgs a) {
  __shared__ float SH[64 * 65];
  int tid = threadIdx.x;
  int b = (int)blockIdx.x;

  if (b == 0) {  // --- weff + RoPE table ---
    float* S = SH;
    for (int i = tid; i < 512; i += 256) S[i] = a.cw[i];
    for (int i = tid; i < 640; i += 256) S[512 + i] = a.nw[i];
    if (tid < 128) { S[1152 + tid] = a.nb[tid]; S[1280 + tid] = a.cb[tid]; }
    __syncthreads();
    if (tid < 128) {
      float acc[11];
#pragma unroll
      for (int r = 0; r < 10; r++) acc[r] = 0.f;
      acc[10] = a.ib[tid];
      for (int k = 0; k < 128; k++) {
        float w = a.iw[k * 128 + tid];
#pragma unroll
        for (int r = 0; r < 11; r++) acc[r] += S[r * 128 + k] * w;
      }
#pragma unroll
      for (int r = 0; r < 11; r++) a.weff[r * 128 + tid] = acc[r];
    }
    for (int idx = tid; idx < 512; idx += 256) {
      int pos = idx >> 4, d = idx & 15;
      float ang = (float)pos * expf(-0.57564627324851148f * (float)d);
      a.ropetab[idx] = cosf(ang);
      a.ropetab[512 + idx] = sinf(ang);
    }
    return;
  }
  b -= 1;
  if (b < a.ubase) {  // --- transpose weight prep ---
    int j = 0;
#pragma unroll
    for (int t = 1; t < 5; t++) if (b >= a.base[t]) j = t;
    int lb = b - a.base[j];
    int K = a.K[j], N = a.N[j];
    int nbx = a.bx[j];
    int perLevel = nbx * a.by[j];
    int z = lb / perLevel;
    int rem = lb - z * perLevel;
    int gx = rem % nbx, gy = rem / nbx;
    size_t off = (size_t)z * K * N;
    const float* src = a.wsrc[j] + off;
    ushort* dst = a.wdst[j] + off;
    int k0 = gx * 64, n0 = gy * 64;
    for (int i = tid; i < 64 * 64; i += 256) {
      int kk = i >> 6, nn = i & 63;
      SH[kk * 65 + nn] = src[(size_t)(k0 + kk) * N + n0 + nn];
    }
    __syncthreads();
    int n = tid >> 2, kq = tid & 3;
    unsigned pk[8];
#pragma unroll
    for (int i = 0; i < 8; i++) {
      int k = kq * 16 + 2 * i;
      pk[i] = f2bf2(SH[k * 65 + n], SH[(k + 1) * 65 + n]);
    }
    unsigned* dp = (unsigned*)&dst[(size_t)(n0 + n) * K + k0 + kq * 16];
#pragma unroll
    for (int i = 0; i < 8; i++) dp[i] = pk[i];
    return;
  }
  {  // --- uv weight prep ---
    int lb = b - a.ubase;
    int mi = lb / 328;
    int gx = lb - mi * 328;
    int i = gx * 256 + tid;
    int expj = a.expj[mi];
    if (i >= a.npad8[mi] * 128) return;
    int n = i >> 7, k = i & 127;
    a.udst[mi][(size_t)n * 128 + k] =
        (n < expj) ? f2bf(a.usrc[mi][(size_t)k * expj + n]) : (ushort)0;
  }
}

// ============ 1. node embedding (collapsed linear form) ====================
__global__ __launch_bounds__(256) void node_embed2_kernel(
    const float* __restrict__ x, const float* __restrict__ weff,
    float* __restrict__ h) {
  __shared__ float XR[64 * XFv];
  __shared__ float RF[64][11];
  __shared__ __align__(16) float WE[11 * 128];
  int tid = threadIdx.x;
  int node0 = blockIdx.x * 64;
  for (int i = tid; i < 64 * XFv; i += 256)
    XR[i] = x[(size_t)node0 * XFv + i];
  for (int i = tid; i < 11 * 128; i += 256) WE[i] = weff[i];
  __syncthreads();
  {
    int nn = tid >> 2, sl = tid & 3;
    const float* xr = XR + nn * XFv;
    float p0 = xr[0], p1 = xr[1], p2 = xr[2];
    float g[6] = {0.f, 0.f, 0.f, 0.f, 0.f, 0.f};
#pragma unroll
    for (int s = 0; s < 6; s++) {
      const float* f = xr + 4 + 5 * (sl * 6 + s);
      float w = f[4];
      if (w != 0.0f) {
        g[0] += f[0]; g[1] += f[1] - p0; g[2] += f[2] - p1;
        g[3] += f[3] - p2; g[4] += w; g[5] += 1.0f;
      }
    }
#pragma unroll
    for (int i = 0; i < 6; i++) {
      g[i] += __shfl_xor(g[i], 1);
      g[i] += __shfl_xor(g[i], 2);
    }
    if (sl == 0) {
      RF[nn][0] = p0; RF[nn][1] = p1; RF[nn][2] = p2; RF[nn][3] = xr[3];
#pragma unroll
      for (int i = 0; i < 6; i++) RF[nn][4 + i] = g[i];
    }
  }
  __syncthreads();
  {
    int w = tid >> 6, lane = tid & 63;
    int c4 = lane & 31, hi = lane >> 5;
    const float4* WE4 = (const float4*)WE;
#pragma unroll
    for (int rr = 0; rr < 8; rr++) {
      int node = w * 16 + rr * 2 + hi;
      float4 acc = WE4[10 * 32 + c4];
#pragma unroll
      for (int f = 0; f < 10; f++)
        fma4(acc, RF[node][f], WE4[f * 32 + c4]);
      *(float4*)&h[(size_t)(node0 + node) * 128 + c4 * 4] = acc;
    }
  }
}

// ============================ 2. leaf dense ================================
__global__ __launch_bounds__(256) void leaf_dense_kernel(
    const float* __restrict__ h, const float* __restrict__ x,
    const float* __restrict__ lpw, const float* __restrict__ lpb,
    const float* __restrict__ lhw, const float* __restrict__ lhb,
    const float* __restrict__ lsc, float* __restrict__ out) {
  __shared__ __align__(16) float HS[32 * 128];
  __shared__ __align__(16) float HL[32 * 32];
  __shared__ __align__(16) float UL[32 * 32];
  int tid = threadIdx.x;
  int leaf = blockIdx.x;
  size_t base = (size_t)leaf * (32 * 128);
  for (int i = tid; i < 32 * 128; i += 256) {
    int t = i >> 7, c = i & 127;
    at1r(HS, t, c, 128) = h[base + i];
  }
  __syncthreads();
  int t = tid & 31, cg = tid >> 5;
  {
    float4 acc = ld4g(&lpb[4 * cg]);
    for (int k4 = 0; k4 < 128; k4 += 4) {
      float4 xv = *(const float4*)at4p(HS, t, k4, 128);
      float xa[4] = {xv.x, xv.y, xv.z, xv.w};
#pragma unroll
      for (int kk = 0; kk < 4; kk++)
        fma4(acc, xa[kk], ld4g(&lpw[(k4 + kk) * 32 + 4 * cg]));
    }
    *(float4*)at4p(HL, t, 4 * cg, 32) = acc;
  }
  __syncthreads();
  {
    float4 acc = ld4g(&lhb[4 * cg]);
    for (int k4 = 0; k4 < 32; k4 += 4) {
      float4 xv = *(const float4*)at4p(HL, t, k4, 32);
      float xa[4] = {xv.x, xv.y, xv.z, xv.w};
#pragma unroll
      for (int kk = 0; kk < 4; kk++)
        fma4(acc, xa[kk], ld4g(&lhw[(k4 + kk) * 32 + 4 * cg]));
    }
    *(float4*)at4p(UL, t, 4 * cg, 32) = acc;
  }
  __syncthreads();
  {
    float scale = expf(lsc[0]);
    float acc[4] = {0.f, 0.f, 0.f, 0.f};
    for (int k4 = 0; k4 < 32; k4 += 4) {
      float4 xv = *(const float4*)at4p(UL, t, k4, 32);
      float xa[4] = {xv.x, xv.y, xv.z, xv.w};
#pragma unroll
      for (int kk = 0; kk < 4; kk++) {
        int k = k4 + kk;
#pragma unroll
        for (int i2 = 0; i2 < 4; i2++)
          acc[i2] += xa[kk] * at1r(UL, 4 * cg + i2, k, 32);
      }
    }
    int b = leaf >> 8, l = leaf & 255;
#pragma unroll
    for (int i2 = 0; i2 < 4; i2++) {
      int c = 4 * cg + i2;
      float v = acc[i2] * scale;
      if (c == t) {
        float dg = x[(size_t)(leaf * 32 + t) * XFv + 3];
        v += (fabsf(dg) > 1e-6f) ? (1.0f / dg) : 1.0f;
      }
      out[(size_t)b * OPB + (size_t)l * 1024 + t * 32 + c] = v;
    }
  }
}

// ========== 3. fused transformer layer: attn + mlp (32-token tiles) ========
// Round-9 proven structure (best counters). cvt_pk bf16 conversions,
// 256-thread softmax, double-buffered mlp (1 barrier/chunk).
__global__ __launch_bounds__(256, 4) void layer_mfma_kernel(
    float* __restrict__ h,
    const float* __restrict__ lng, const float* __restrict__ lnb,
    const ushort* __restrict__ wqkvt, const float* __restrict__ bqkv,
    const ushort* __restrict__ wpt, const float* __restrict__ pb,
    const float* __restrict__ rt,
    const float* __restrict__ ln2g, const float* __restrict__ ln2b,
    const ushort* __restrict__ w1t, const float* __restrict__ b1,
    const ushort* __restrict__ w2t, const float* __restrict__ b2) {
  __shared__ __align__(16) ushort SM[20480];   // 40 KB
  ushort* XN = SM;            // R0 [0,8KB)
  ushort* QB = SM + 4096;     // R1 [8,16KB)
  ushort* KB = SM + 8192;     // R2 [16,24KB)
  ushort* VT = SM + 12288;    // R3 [24,32KB)
  ushort* HC1 = SM + 16384;   // R4 [32,40KB) (mlp hidden buf 1)
  float*  HS = (float*)(SM + 8192);   // fp32 32x128 over R2+R3
  int tid = threadIdx.x;
  size_t base = (size_t)blockIdx.x * (32 * 128);
  int w = tid >> 6, l = tid & 63, lm = l & 15, q = l >> 4;

  { // --- A: LayerNorm1 -> bf16 XN (8 threads/token, 16 cols each) ---
    int m8 = tid >> 3, p8 = tid & 7;
    const float* row = h + base + m8 * 128 + p8 * 16;
    float v[16];
    float s = 0.f;
#pragma unroll
    for (int i = 0; i < 16; i += 4) {
      float4 t4 = ld4g(row + i);
      v[i] = t4.x; v[i + 1] = t4.y; v[i + 2] = t4.z; v[i + 3] = t4.w;
      s += t4.x + t4.y + t4.z + t4.w;
    }
    s += __shfl_xor(s, 1); s += __shfl_xor(s, 2); s += __shfl_xor(s, 4);
    float mu = s * (1.0f / 128.0f);
    float s2 = 0.f;
#pragma unroll
    for (int i = 0; i < 16; i++) { float d = v[i] - mu; s2 += d * d; }
    s2 += __shfl_xor(s2, 1); s2 += __shfl_xor(s2, 2); s2 += __shfl_xor(s2, 4);
    float rs = rsqrtf(s2 * (1.0f / 128.0f) + 1e-5f);
    unsigned* XW = (unsigned*)XN;
#pragma unroll
    for (int i = 0; i < 16; i += 2) {
      int c = p8 * 16 + i;
      float x0 = (v[i] - mu) * rs * lng[c] + lnb[c];
      float x1 = (v[i + 1] - mu) * rs * lng[c + 1] + lnb[c + 1];
      int kp = c >> 1;
      XW[m8 * 64 + ((kp + 4 * m8) & 63)] = f2bf2(x0, x1);
    }
  }
  __syncthreads();

  { // --- B: qkv GEMM (M=32) + RoPE via table ---
    f32x4v acc[2][6];
#pragma unroll
    for (int mt = 0; mt < 2; mt++)
#pragma unroll
      for (int nt = 0; nt < 6; nt++) acc[mt][nt] = (f32x4v){0.f, 0.f, 0.f, 0.f};
    for (int ks = 0; ks < 4; ks++) {
      bfrag a[2];
#pragma unroll
      for (int mt = 0; mt < 2; mt++) {
        int mm = mt * 16 + lm;
        a[mt] = *(const bfrag*)&XN[mm * 128 + ((ks * 32 + q * 8 + 8 * mm) & 127)];
      }
#pragma unroll
      for (int nt = 0; nt < 6; nt++) {
        int n = w * 96 + nt * 16 + lm;
        bfrag b = *(const bfrag*)&wqkvt[(size_t)n * 128 + ks * 32 + q * 8];
#pragma unroll
        for (int mt = 0; mt < 2; mt++)
          acc[mt][nt] = __builtin_amdgcn_mfma_f32_16x16x32_bf16(
              a[mt], b, acc[mt][nt], 0, 0, 0);
      }
    }
    float csA[4] = {}, snA[4] = {}, csB[4] = {}, snB[4] = {};
    if (w < 3) {   // only q/k waves rotate
#pragma unroll
      for (int r = 0; r < 4; r++) {
        int pa = q * 4 + r;
        csA[r] = rt[pa * 16 + lm];        snA[r] = rt[512 + pa * 16 + lm];
        csB[r] = rt[(pa + 16) * 16 + lm]; snB[r] = rt[512 + (pa + 16) * 16 + lm];
      }
    }
#pragma unroll
    for (int p2 = 0; p2 < 3; p2++) {
      int g = w * 6 + 2 * p2;
      int ne = g * 16 + lm;
      if (g < 16) {
        float be = bqkv[ne], bo = bqkv[ne + 16];
        ushort* dst = (g < 8) ? QB : KB;
        int de = (g < 8) ? ne : ne - 128;
#pragma unroll
        for (int mt = 0; mt < 2; mt++)
#pragma unroll
          for (int r = 0; r < 4; r++) {
            int mm = mt * 16 + q * 4 + r;
            float cs = (mt & 1) ? csB[r] : csA[r];
            float sn = (mt & 1) ? snB[r] : snA[r];
            float e = acc[mt][2 * p2][r] + be;
            float o = acc[mt][2 * p2 + 1][r] + bo;
            stb128(dst, mm, de, e * cs - o * sn);
            stb128(dst, mm, de + 16, o * cs + e * sn);
          }
      } else {
#pragma unroll
        for (int h2 = 0; h2 < 2; h2++) {
          int nt = 2 * p2 + h2;
          int nv = (g + h2) * 16 + lm;
          int dv = nv - 256;
          float bv = bqkv[nv];
#pragma unroll
          for (int mt = 0; mt < 2; mt++) {
            int t0 = mt * 16 + q * 4;
            uint2 pk;
            pk.x = f2bf2(acc[mt][nt][0] + bv, acc[mt][nt][1] + bv);
            pk.y = f2bf2(acc[mt][nt][2] + bv, acc[mt][nt][3] + bv);
            *(uint2*)&VT[dv * 32 + (((t0 & ~7) + 8 * dv) & 31) + (t0 & 7)] = pk;
          }
        }
      }
    }
  }
  __syncthreads();

  ushort* SP = XN;   // scores overlay XN (dead after B)
  { // --- C: scores (wave = head) ---
    int head = w;
    f32x4v sc[2][2];
#pragma unroll
    for (int a2 = 0; a2 < 2; a2++)
#pragma unroll
      for (int b2 = 0; b2 < 2; b2++) sc[a2][b2] = (f32x4v){0.f, 0.f, 0.f, 0.f};
    bfrag qa[2], kb[2];
#pragma unroll
    for (int mt2 = 0; mt2 < 2; mt2++) {
      int row = mt2 * 16 + lm;
      qa[mt2] = *(const bfrag*)&QB[row * 128 + ((head * 32 + q * 8 + 8 * row) & 127)];
    }
#pragma unroll
    for (int nt2 = 0; nt2 < 2; nt2++) {
      int kt = nt2 * 16 + lm;
      kb[nt2] = *(const bfrag*)&KB[kt * 128 + ((head * 32 + q * 8 + 8 * kt) & 127)];
    }
#pragma unroll
    for (int mt2 = 0; mt2 < 2; mt2++)
#pragma unroll
      for (int nt2 = 0; nt2 < 2; nt2++)
        sc[mt2][nt2] = __builtin_amdgcn_mfma_f32_16x16x32_bf16(
            qa[mt2], kb[nt2], sc[mt2][nt2], 0, 0, 0);
    const float scl = 0.17677669529663688f;
#pragma unroll
    for (int mt2 = 0; mt2 < 2; mt2++)
#pragma unroll
      for (int nt2 = 0; nt2 < 2; nt2++)
#pragma unroll
        for (int r = 0; r < 4; r++) {
          int qt = mt2 * 16 + q * 4 + r;
          int kc = nt2 * 16 + lm;
          SP[head * 1024 + qt * 32 + (((kc & ~7) + 8 * qt) & 31) + (kc & 7)] =
              f2bf(sc[mt2][nt2][r] * scl);
        }
  }
  __syncthreads();

  { // --- D: softmax (all 256 threads: 2 threads per row) ---
    int rowid = tid >> 1, half = tid & 1;
    int head = rowid >> 5, qt = rowid & 31;
    ushort* rowp = SP + head * 1024 + qt * 32 + half * 16;
    float v[16];
#pragma unroll
    for (int pc = 0; pc < 2; pc++) {
      uint4 ch = *(const uint4*)&rowp[pc * 8];
      unsigned uu[4] = {ch.x, ch.y, ch.z, ch.w};
#pragma unroll
      for (int i2 = 0; i2 < 4; i2++) {
        v[pc * 8 + 2 * i2]     = __uint_as_float(uu[i2] << 16);
        v[pc * 8 + 2 * i2 + 1] = __uint_as_float(uu[i2] & 0xffff0000u);
      }
    }
    float mx = -1e30f;
#pragma unroll
    for (int i = 0; i < 16; i++) mx = fmaxf(mx, v[i]);
    mx = fmaxf(mx, __shfl_xor(mx, 1));
    float s = 0.f;
#pragma unroll
    for (int i = 0; i < 16; i++) { v[i] = __expf(v[i] - mx); s += v[i]; }
    s += __shfl_xor(s, 1);
    float inv = 1.0f / s;
#pragma unroll
    for (int pc = 0; pc < 2; pc++) {
      uint4 ch;
      unsigned uu[4];
#pragma unroll
      for (int i2 = 0; i2 < 4; i2++)
        uu[i2] = f2bf2(v[pc * 8 + 2 * i2] * inv, v[pc * 8 + 2 * i2 + 1] * inv);
      ch.x = uu[0]; ch.y = uu[1]; ch.z = uu[2]; ch.w = uu[3];
      *(uint4*)&rowp[pc * 8] = ch;
    }
  }
  __syncthreads();

  ushort* OB = QB;   // attn-out overlays QB (dead after C)
  { // --- E: O = P @ V (wave = head) ---
    int head = w;
    f32x4v ov[2][2];
#pragma unroll
    for (int a2 = 0; a2 < 2; a2++)
#pragma unroll
      for (int b2 = 0; b2 < 2; b2++) ov[a2][b2] = (f32x4v){0.f, 0.f, 0.f, 0.f};
    bfrag pa[2], vb2[2];
#pragma unroll
    for (int mt2 = 0; mt2 < 2; mt2++) {
      int qt = mt2 * 16 + lm;
      pa[mt2] = *(const bfrag*)&SP[head * 1024 + qt * 32 + ((q * 8 + 8 * qt) & 31)];
    }
#pragma unroll
    for (int nt2 = 0; nt2 < 2; nt2++) {
      int gdim = head * 32 + nt2 * 16 + lm;
      vb2[nt2] = *(const bfrag*)&VT[gdim * 32 + ((q * 8 + 8 * gdim) & 31)];
    }
#pragma unroll
    for (int mt2 = 0; mt2 < 2; mt2++)
#pragma unroll
      for (int nt2 = 0; nt2 < 2; nt2++)
        ov[mt2][nt2] = __builtin_amdgcn_mfma_f32_16x16x32_bf16(
            pa[mt2], vb2[nt2], ov[mt2][nt2], 0, 0, 0);
#pragma unroll
    for (int mt2 = 0; mt2 < 2; mt2++)
#pragma unroll
      for (int nt2 = 0; nt2 < 2; nt2++)
#pragma unroll
        for (int r = 0; r < 4; r++) {
          int qt = mt2 * 16 + q * 4 + r;
          int gdim = head * 32 + nt2 * 16 + lm;
          stb128(OB, qt, gdim, ov[mt2][nt2][r]);
        }
  }
  __syncthreads();

  { // --- F: out-proj -> HS = attn_out + pb (fp32, 4-rotated rows) ---
    f32x4v po[2][2];
#pragma unroll
    for (int mt = 0; mt < 2; mt++)
#pragma unroll
      for (int nt = 0; nt < 2; nt++) po[mt][nt] = (f32x4v){0.f, 0.f, 0.f, 0.f};
    for (int ks = 0; ks < 4; ks++) {
      bfrag a[2];
#pragma unroll
      for (int mt = 0; mt < 2; mt++) {
        int mm = mt * 16 + lm;
        a[mt] = *(const bfrag*)&OB[mm * 128 + ((ks * 32 + q * 8 + 8 * mm) & 127)];
      }
#pragma unroll
      for (int nt = 0; nt < 2; nt++) {
        int n = w * 32 + nt * 16 + lm;
        bfrag b = *(const bfrag*)&wpt[(size_t)n * 128 + ks * 32 + q * 8];
#pragma unroll
        for (int mt = 0; mt < 2; mt++)
          po[mt][nt] = __builtin_amdgcn_mfma_f32_16x16x32_bf16(
              a[mt], b, po[mt][nt], 0, 0, 0);
      }
    }
#pragma unroll
    for (int nt = 0; nt < 2; nt++) {
      int n = w * 32 + nt * 16 + lm;
      float bv = pb[n];
#pragma unroll
      for (int mt = 0; mt < 2; mt++)
#pragma unroll
        for (int r = 0; r < 4; r++) {
          int mm = mt * 16 + q * 4 + r;
          at1r(HS, mm, n, 128) = po[mt][nt][r] + bv;
        }
    }
  }
  __syncthreads();

  { // --- G: hn = h + attn_out (in HS); LayerNorm2 -> bf16 XN2 ---
    int j = tid & 31;
    int c0 = j * 4;
    float g0 = ln2g[c0], g1 = ln2g[c0 + 1], g2 = ln2g[c0 + 2], g3 = ln2g[c0 + 3];
    float e0 = ln2b[c0], e1 = ln2b[c0 + 1], e2 = ln2b[c0 + 2], e3 = ln2b[c0 + 3];
    unsigned* XW = (unsigned*)XN;
#pragma unroll
    for (int k2 = 0; k2 < 4; k2++) {
      int idx = tid + 256 * k2;
      int tok = idx >> 5;
      float4 hg = ld4g(&h[base + (size_t)idx * 4]);
      float4 ao = *(const float4*)at4p(HS, tok, 4 * j, 128);
      float4 hn;
      hn.x = hg.x + ao.x; hn.y = hg.y + ao.y;
      hn.z = hg.z + ao.z; hn.w = hg.w + ao.w;
      *(float4*)at4p(HS, tok, 4 * j, 128) = hn;
      float s = hn.x + hn.y + hn.z + hn.w;
      s += __shfl_xor(s, 1); s += __shfl_xor(s, 2); s += __shfl_xor(s, 4);
      s += __shfl_xor(s, 8); s += __shfl_xor(s, 16);
      float mu = s * (1.0f / 128.0f);
      float d0 = hn.x - mu, d1 = hn.y - mu, d2 = hn.z - mu, d3 = hn.w - mu;
      float s2 = d0 * d0 + d1 * d1 + d2 * d2 + d3 * d3;
      s2 += __shfl_xor(s2, 1); s2 += __shfl_xor(s2, 2); s2 += __shfl_xor(s2, 4);
      s2 += __shfl_xor(s2, 8); s2 += __shfl_xor(s2, 16);
      float rs = rsqrtf(s2 * (1.0f / 128.0f) + 1e-5f);
      float x0 = d0 * rs * g0 + e0;
      float x1 = d1 * rs * g1 + e1;
      float x2 = d2 * rs * g2 + e2;
      float x3 = d3 * rs * g3 + e3;
      int kp = 2 * j;
      XW[tok * 64 + ((kp + 4 * tok) & 63)] = f2bf2(x0, x1);
      XW[tok * 64 + ((kp + 1 + 4 * tok) & 63)] = f2bf2(x2, x3);
    }
  }
  __syncthreads();

  // --- mlp: 4 hidden chunks, double-buffered HC, 1 barrier/chunk ---
  ushort* HC0 = QB;
  f32x4v acc2[2][2];
#pragma unroll
  for (int mt = 0; mt < 2; mt++)
#pragma unroll
    for (int nt = 0; nt < 2; nt++) acc2[mt][nt] = (f32x4v){0.f, 0.f, 0.f, 0.f};

  auto mlp1_calc = [&](int hc, f32x4v A1[2][2]) {
#pragma unroll
    for (int mt = 0; mt < 2; mt++)
#pragma unroll
      for (int nt = 0; nt < 2; nt++) A1[mt][nt] = (f32x4v){0.f, 0.f, 0.f, 0.f};
#pragma unroll
    for (int ks = 0; ks < 4; ks++) {
      bfrag a[2];
#pragma unroll
      for (int mt = 0; mt < 2; mt++) {
        int mm = mt * 16 + lm;
        a[mt] = *(const bfrag*)&XN[mm * 128 + ((ks * 32 + q * 8 + 8 * mm) & 127)];
      }
#pragma unroll
      for (int nt = 0; nt < 2; nt++) {
        int n = hc * 128 + w * 32 + nt * 16 + lm;
        bfrag b = *(const bfrag*)&w1t[(size_t)n * 128 + ks * 32 + q * 8];
#pragma unroll
        for (int mt = 0; mt < 2; mt++)
          A1[mt][nt] = __builtin_amdgcn_mfma_f32_16x16x32_bf16(
              a[mt], b, A1[mt][nt], 0, 0, 0);
      }
    }
  };
  auto gelu_store = [&](int hc, f32x4v A1[2][2], ushort* HCd) {
#pragma unroll
    for (int nt = 0; nt < 2; nt++) {
      int nl = w * 32 + nt * 16 + lm;
      float b1v = b1[hc * 128 + nl];
#pragma unroll
      for (int mt = 0; mt < 2; mt++)
#pragma unroll
        for (int r = 0; r < 4; r++) {
          int mm = mt * 16 + q * 4 + r;
          float val = gelu_fast(A1[mt][nt][r] + b1v);
          HCd[mm * 128 + (((nl & ~7) + 8 * mm) & 127) + (nl & 7)] = f2bf(val);
        }
    }
  };
  auto mlp2_calc = [&](int hc, ushort* HCr) {
#pragma unroll
    for (int ks = 0; ks < 4; ks++) {
      bfrag a[2];
#pragma unroll
      for (int mt = 0; mt < 2; mt++) {
        int mm = mt * 16 + lm;
        a[mt] = *(const bfrag*)&HCr[mm * 128 + ((ks * 32 + q * 8 + 8 * mm) & 127)];
      }
#pragma unroll
      for (int nt = 0; nt < 2; nt++) {
        int n = w * 32 + nt * 16 + lm;
        bfrag b = *(const bfrag*)&w2t[(size_t)n * 512 + hc * 128 + ks * 32 + q * 8];
#pragma unroll
        for (int mt = 0; mt < 2; mt++)
          acc2[mt][nt] = __builtin_amdgcn_mfma_f32_16x16x32_bf16(
              a[mt], b, acc2[mt][nt], 0, 0, 0);
      }
    }
  };

  f32x4v a1A[2][2], a1B[2][2];
  mlp1_calc(0, a1A);
  gelu_store(0, a1A, HC0);
  __syncthreads();
  mlp1_calc(1, a1B);        // overlaps with other waves' mlp2(0)
  mlp2_calc(0, HC0);
  gelu_store(1, a1B, HC1);
  __syncthreads();
  mlp1_calc(2, a1A);
  mlp2_calc(1, HC1);
  gelu_store(2, a1A, HC0);
  __syncthreads();
  mlp1_calc(3, a1B);
  mlp2_calc(2, HC0);
  gelu_store(3, a1B, HC1);
  __syncthreads();
  mlp2_calc(3, HC1);

  // --- epilogue: h = hn (HS) + mlp_out + b2 — the ONLY global h write ---
#pragma unroll
  for (int nt = 0; nt < 2; nt++) {
    int n = w * 32 + nt * 16 + lm;
    float b2v = b2[n];
#pragma unroll
    for (int mt = 0; mt < 2; mt++)
#pragma unroll
      for (int r = 0; r < 4; r++) {
        int mm = mt * 16 + q * 4 + r;
        h[base + (size_t)mm * 128 + n] = at1r(HS, mm, n, 128) + acc2[mt][nt][r] + b2v;
      }
  }
}

// ====== 5. uv heads + downsample, fused (64-token tiles, compact stg) ======
template <int EXPJ, int RANK, int LVL, int NSPLIT>
__global__ __launch_bounds__(256) void uvds_kernel(
    const float* __restrict__ h,
    const ushort* __restrict__ uwt, const float* __restrict__ ub,
    const ushort* __restrict__ vwt, const float* __restrict__ vb,
    float* __restrict__ ustg, float* __restrict__ vstg,
    float* __restrict__ hout,
    const ushort* __restrict__ dwt, const float* __restrict__ dsb) {
  constexpr int NT16 = (EXPJ + 15) / 16;
  constexpr int NJOBS = 2 * NT16;
  __shared__ __align__(16) ushort XN[64 * 128];
  int tid = threadIdx.x;
  int t0 = blockIdx.x * 64;
  size_t base = (size_t)t0 * 128;
  {
    int m = tid >> 2, p = tid & 3;
    const float* row = h + base + m * 128 + p * 32;
    unsigned* XW = (unsigned*)XN;
#pragma unroll
    for (int i = 0; i < 32; i += 4) {
      float4 t4 = ld4g(row + i);
      int kp = (p * 32 + i) >> 1;
      XW[m * 64 + ((kp + 4 * m) & 63)] = f2bf2(t4.x, t4.y);
      XW[m * 64 + ((kp + 1 + 4 * m) & 63)] = f2bf2(t4.z, t4.w);
    }
  }
  __syncthreads();
  int w = tid >> 6, l = tid & 63, lm = l & 15, q = l >> 4;
  int gw = w + 4 * blockIdx.y;
  for (int jj = gw; jj < NJOBS; jj += 4 * NSPLIT) {
    int uvsel = jj & 1, nt = jj >> 1;
    const ushort* wt = uvsel ? vwt : uwt;
    const float* bias = uvsel ? vb : ub;
    float* stg = uvsel ? vstg : ustg;
    f32x4v acc[4];
#pragma unroll
    for (int mt = 0; mt < 4; mt++) acc[mt] = (f32x4v){0.f, 0.f, 0.f, 0.f};
    for (int ks = 0; ks < 4; ks++) {
      bfrag b = *(const bfrag*)&wt[(size_t)(nt * 16 + lm) * 128 + ks * 32 + q * 8];
#pragma unroll
      for (int mt = 0; mt < 4; mt++) {
        int mm = mt * 16 + lm;
        int ke = ks * 32 + q * 8;
        bfrag a = *(const bfrag*)&XN[mm * 128 + ((ke + 8 * mm) & 127)];
        acc[mt] = __builtin_amdgcn_mfma_f32_16x16x32_bf16(a, b, acc[mt], 0, 0, 0);
      }
    }
    int c = nt * 16 + lm;
    if (c < EXPJ) {
      float bv = bias[c];
#pragma unroll
      for (int mt = 0; mt < 4; mt++)
#pragma unroll
        for (int r = 0; r < 4; r++) {
          int mm = mt * 16 + q * 4 + r;
          stg[(size_t)(t0 + mm) * EXPJ + c] = acc[mt][r] + bv;
        }
    }
  }
  if constexpr (LVL < 3) {
    if (blockIdx.y == 0) { // --- downsample: 64 tokens -> 32 rows of 128 ---
      f32x4v dacc[2][2];
#pragma unroll
      for (int mt = 0; mt < 2; mt++)
#pragma unroll
        for (int nt = 0; nt < 2; nt++) dacc[mt][nt] = (f32x4v){0.f, 0.f, 0.f, 0.f};
      for (int ks = 0; ks < 8; ks++) {
        bfrag a[2];
#pragma unroll
        for (int mt = 0; mt < 2; mt++) {
          int rr = mt * 16 + lm;
          int tok = 2 * rr + (ks >> 2);
          int c2 = (ks & 3) * 32 + q * 8;
          a[mt] = *(const bfrag*)&XN[tok * 128 + ((c2 + 8 * tok) & 127)];
        }
#pragma unroll
        for (int nt = 0; nt < 2; nt++) {
          int n = w * 32 + nt * 16 + lm;
          bfrag b = *(const bfrag*)&dwt[(size_t)n * 256 + ks * 32 + q * 8];
#pragma unroll
          for (int mt = 0; mt < 2; mt++)
            dacc[mt][nt] = __builtin_amdgcn_mfma_f32_16x16x32_bf16(
                a[mt], b, dacc[mt][nt], 0, 0, 0);
        }
      }
      size_t ob2 = (size_t)blockIdx.x * (32 * 128);
#pragma unroll
      for (int nt = 0; nt < 2; nt++) {
        int n = w * 32 + nt * 16 + lm;
        float bv = dsb[n];
#pragma unroll
        for (int mt = 0; mt < 2; mt++)
#pragma unroll
          for (int r = 0; r < 4; r++) {
            int mm = mt * 16 + q * 4 + r;
            hout[ob2 + (size_t)mm * 128 + n] = dacc[mt][nt][r] + bv;
          }
      }
    }
  }
}

// ====== 6. final uv assembly: staging -> out rows, fully contiguous ========
struct StgPtrs { const float* u[4]; const float* v[4]; };
__global__ __launch_bounds__(256) void uv_assemble_kernel(
    StgPtrs sp, float* __restrict__ out) {
  __shared__ unsigned char JL[93];
  __shared__ unsigned char CM[93];
  int tid = threadIdx.x;
  if (tid < 93) {
    int c = 2 * tid;
    int j = (c < 20) ? 0 : (c < 52) ? 1 : (c < 104) ? 2 : 3;
    int coff = (j == 0) ? 0 : (j == 1) ? 20 : (j == 2) ? 52 : 104;
    JL[tid] = (unsigned char)j;
    CM[tid] = (unsigned char)(c - coff);
  }
  __syncthreads();
  int g0 = blockIdx.x * 32;   // 32 global node-rows per block
  for (int i = tid; i < 32 * 93; i += 256) {
    int rr = i / 93, cp = i - rr * 93;
    int g = g0 + rr;
    int b = g >> 13, n = g & 8191;
    int j = JL[cp], cm = CM[cp];
    int expj, rank;
    if (j == 0)      { expj = 20;  rank = 20; }
    else if (j == 1) { expj = 64;  rank = 32; }
    else if (j == 2) { expj = 208; rank = 52; }
    else             { expj = 656; rank = 82; }
    int tok = (b << (13 - j)) + (n >> j);
    int cdiv = n & ((1 << j) - 1);
    size_t si = (size_t)tok * expj + cdiv * rank + cm;
    size_t ob = (size_t)b * OPB + (size_t)n * UVWID + 2 * cp;
    *(float2*)&out[ob + UBASE] = *(const float2*)&sp.u[j][si];
    *(float2*)&out[ob + VBASE] = *(const float2*)&sp.v[j][si];
  }
}

// ================================ host =====================================
extern "C" void kernel_launch(void* const* d_in, const int* in_sizes, int n_in,
                              void* d_out, int out_size, void* d_ws, size_t ws_size,
                              hipStream_t stream) {
  const float* x       = (const float*)d_in[0];
  const float* cen_w   = (const float*)d_in[1];
  const float* cen_b   = (const float*)d_in[2];
  const float* nbr_w   = (const float*)d_in[3];
  const float* nbr_b   = (const float*)d_in[4];
  const float* inp_w   = (const float*)d_in[5];
  const float* inp_b   = (const float*)d_in[6];
  const float* leafp_w = (const float*)d_in[7];
  const float* leafp_b = (const float*)d_in[8];
  const float* leafh_w = (const float*)d_in[9];
  const float* leafh_b = (const float*)d_in[10];
  const float* lscale  = (const float*)d_in[11];
  const float* ln1_g   = (const float*)d_in[12];
  const float* ln1_b   = (const float*)d_in[13];
  const float* qkv_w   = (const float*)d_in[14];
  const float* qkv_b   = (const float*)d_in[15];
  const float* attnp_w = (const float*)d_in[16];
  const float* attnp_b = (const float*)d_in[17];
  const float* ln2_g   = (const float*)d_in[18];
  const float* ln2_b   = (const float*)d_in[19];
  const float* mlp1_w  = (const float*)d_in[20];
  const float* mlp1_b  = (const float*)d_in[21];
  const float* mlp2_w  = (const float*)d_in[22];
  const float* mlp2_b  = (const float*)d_in[23];
  const float* ds_w    = (const float*)d_in[24];
  const float* ds_b    = (const float*)d_in[25];
  const float* huw[4], *hub[4], *hvw[4], *hvb[4];
  for (int j = 0; j < 4; j++) {
    huw[j] = (const float*)d_in[26 + 4 * j];
    hub[j] = (const float*)d_in[27 + 4 * j];
    hvw[j] = (const float*)d_in[28 + 4 * j];
    hvb[j] = (const float*)d_in[29 + 4 * j];
  }
  float* out = (float*)d_out;
  float* hA = (float*)d_ws;                       // 4*8192*128 fp32 = 16 MB
  float* hB = hA + (size_t)4 * 8192 * 128;        // 8 MB (ping-pong)
  ushort* w1t = (ushort*)(hB + (size_t)2097152);
  ushort* w2t = w1t + (size_t)4 * 65536;
  ushort* uvt = w2t + (size_t)4 * 65536;
  const int NPAD[4] = {32, 64, 208, 656};
  ushort* uwt[4]; ushort* vwt[4];
  ushort* p = uvt;
  for (int j = 0; j < 4; j++) {
    uwt[j] = p; p += (size_t)NPAD[j] * 128;
    vwt[j] = p; p += (size_t)NPAD[j] * 128;
  }
  ushort* wqkvt = p;                              // 4 levels x 384x128 bf16
  ushort* wpt   = wqkvt + (size_t)4 * 384 * 128;  // 4 levels x 128x128 bf16
  ushort* dswt  = wpt + (size_t)4 * 128 * 128;    // 4 levels x 128x256 bf16
  float* weff   = (float*)(dswt + (size_t)4 * 128 * 256);   // 11 x 128 fp32
  float* ropetab = weff + 1408;                   // 1024 floats
  // uv staging: [global_token][EXPJ] fp32 per level (u and v)
  const size_t STG[4] = {32768ull * 20, 16384ull * 64, 8192ull * 208, 4096ull * 656};
  float* ustg[4]; float* vstg[4];
  float* sp2 = ropetab + 1024;
  for (int j = 0; j < 4; j++) {
    ustg[j] = sp2; sp2 += STG[j];
    vstg[j] = sp2; sp2 += STG[j];
  }
  const int EXPJ_[4] = {20, 64, 208, 656};

  // stage 0: ALL weight prep in one launch
  {
    PrepArgs pa;
    pa.cw = cen_w; pa.cb = cen_b; pa.nw = nbr_w; pa.nb = nbr_b;
    pa.iw = inp_w; pa.ib = inp_b; pa.weff = weff; pa.ropetab = ropetab;
    const float* WS[5] = {mlp1_w, mlp2_w, qkv_w, attnp_w, ds_w};
    ushort* WD[5] = {w1t, w2t, wqkvt, wpt, dswt};
    const int KK[5] = {128, 512, 128, 128, 256};
    const int NN[5] = {512, 128, 384, 128, 128};
    const int BX[5] = {2, 8, 2, 2, 4};
    const int BY[5] = {8, 2, 6, 2, 2};
    int cum = 0;
    for (int j2 = 0; j2 < 5; j2++) {
      pa.wsrc[j2] = WS[j2]; pa.wdst[j2] = WD[j2];
      pa.K[j2] = KK[j2]; pa.N[j2] = NN[j2];
      pa.bx[j2] = BX[j2]; pa.by[j2] = BY[j2];
      pa.base[j2] = cum;
      cum += BX[j2] * BY[j2] * 4;
    }
    pa.ubase = cum;   // 224
    for (int j2 = 0; j2 < 4; j2++) {
      pa.usrc[2 * j2] = huw[j2];     pa.udst[2 * j2] = uwt[j2];
      pa.usrc[2 * j2 + 1] = hvw[j2]; pa.udst[2 * j2 + 1] = vwt[j2];
      pa.expj[2 * j2] = EXPJ_[j2];   pa.expj[2 * j2 + 1] = EXPJ_[j2];
      pa.npad8[2 * j2] = NPAD[j2];   pa.npad8[2 * j2 + 1] = NPAD[j2];
    }
    prep_all_kernel<<<1 + cum + 328 * 8, 256, 0, stream>>>(pa);
  }

  // stage 1: node embedding -> hA
  node_embed2_kernel<<<(4 * 8192) / 64, 256, 0, stream>>>(x, weff, hA);
  // stage 2: leaf dense Gram
  leaf_dense_kernel<<<(4 * 8192) / 32, 256, 0, stream>>>(
      hA, x, leafp_w, leafp_b, leafh_w, leafh_b, lscale, out);

  // stage 3: 4 levels: fused attn+mlp layer, then fused uv+ds
  layer_mfma_kernel<<<32768 / 32, 256, 0, stream>>>(
      hA, ln1_g, ln1_b, wqkvt, qkv_b, wpt, attnp_b, ropetab,
      ln2_g, ln2_b, w1t, mlp1_b, w2t, mlp2_b);
  uvds_kernel<20, 20, 0, 1><<<dim3(512, 1), 256, 0, stream>>>(
      hA, uwt[0], hub[0], vwt[0], hvb[0], ustg[0], vstg[0],
      hB, dswt, ds_b);

  layer_mfma_kernel<<<16384 / 32, 256, 0, stream>>>(
      hB, ln1_g + 128, ln1_b + 128, wqkvt + 49152, qkv_b + 384,
      wpt + 16384, attnp_b + 128, ropetab,
      ln2_g + 128, ln2_b + 128, w1t + 65536, mlp1_b + 512,
      w2t + 65536, mlp2_b + 128);
  uvds_kernel<64, 32, 1, 2><<<dim3(256, 2), 256, 0, stream>>>(
      hB, uwt[1], hub[1], vwt[1], hvb[1], ustg[1], vstg[1],
      hA, dswt + 32768, ds_b + 128);

  layer_mfma_kernel<<<8192 / 32, 256, 0, stream>>>(
      hA, ln1_g + 256, ln1_b + 256, wqkvt + 98304, qkv_b + 768,
      wpt + 32768, attnp_b + 256, ropetab,
      ln2_g + 256, ln2_b + 256, w1t + 131072, mlp1_b + 1024,
      w2t + 131072, mlp2_b + 256);
  uvds_kernel<208, 52, 2, 4><<<dim3(128, 4), 256, 0, stream>>>(
      hA, uwt[2], hub[2], vwt[2], hvb[2], ustg[2], vstg[2],
      hB, dswt + 65536, ds_b + 256);

  layer_mfma_kernel<<<4096 / 32, 256, 0, stream>>>(
      hB, ln1_g + 384, ln1_b + 384, wqkvt + 147456, qkv_b + 1152,
      wpt + 49152, attnp_b + 384, ropetab,
      ln2_g + 384, ln2_b + 384, w1t + 196608, mlp1_b + 1536,
      w2t + 196608, mlp2_b + 384);
  uvds_kernel<656, 82, 3, 8><<<dim3(64, 8), 256, 0, stream>>>(
      hB, uwt[3], hub[3], vwt[3], hvb[3], ustg[3], vstg[3],
      hA /*unused*/, dswt /*unused*/, ds_b /*unused*/);

  // final: assemble uv rows contiguously
  {
    StgPtrs sp;
    for (int j = 0; j < 4; j++) { sp.u[j] = ustg[j]; sp.v[j] = vstg[j]; }
    uv_assemble_kernel<<<32768 / 32, 256, 0, stream>>>(sp, out);
  }
  (void)in_sizes; (void)n_in; (void)out_size; (void)ws_size;
}